// Round 1
// baseline (488.888 us; speedup 1.0000x reference)
//
#include <hip/hip_runtime.h>
#include <hip/hip_bf16.h>
#include <math.h>

#define S_LEN 2048
#define D_DIM 1024
#define NHEAD 16

typedef __attribute__((ext_vector_type(8))) short bf16x8;
typedef __attribute__((ext_vector_type(4))) float floatx4;

__device__ __forceinline__ short f32_bf16(float f) {
  union { float f; unsigned u; } v; v.f = f;
  unsigned r = v.u + 0x7FFFu + ((v.u >> 16) & 1u);
  return (short)(r >> 16);
}

__device__ __forceinline__ void gload16(const void* g, void* l) {
  __builtin_amdgcn_global_load_lds((const __attribute__((address_space(1))) unsigned*)g,
                                   (__attribute__((address_space(3))) unsigned*)l,
                                   16, 0, 0);
}

// ---------------- RMSNorm (fp32 in -> bf16 out) ----------------
__global__ __launch_bounds__(256) void rmsnorm_k(const float* __restrict__ x,
                                                 const float* __restrict__ w,
                                                 short* __restrict__ out) {
  int row = blockIdx.x;
  const float4* xr = (const float4*)(x + (size_t)row * D_DIM);
  float4 v = xr[threadIdx.x];
  float ss = v.x*v.x + v.y*v.y + v.z*v.z + v.w*v.w;
  #pragma unroll
  for (int off = 32; off > 0; off >>= 1) ss += __shfl_xor(ss, off);
  __shared__ float red[4];
  if ((threadIdx.x & 63) == 0) red[threadIdx.x >> 6] = ss;
  __syncthreads();
  float scale = rsqrtf((red[0]+red[1]+red[2]+red[3]) * (1.f/D_DIM) + 1e-6f);
  float4 wv = ((const float4*)w)[threadIdx.x];
  short4 o;
  o.x = f32_bf16(v.x*scale*wv.x);
  o.y = f32_bf16(v.y*scale*wv.y);
  o.z = f32_bf16(v.z*scale*wv.z);
  o.w = f32_bf16(v.w*scale*wv.w);
  ((short4*)out)[(size_t)row*256 + threadIdx.x] = o;
}

// ---------------- weight repack: B^T layout, bf16 ----------------
__global__ __launch_bounds__(256) void pack_wqkv_k(const float* __restrict__ wq,
                                                   const float* __restrict__ wk,
                                                   const float* __restrict__ wv,
                                                   short* __restrict__ o) {
  int t = blockIdx.x*256 + threadIdx.x;   // 3072*1024 elements
  int n = t >> 10, k = t & 1023;
  const float* src = (n < 1024) ? wq : ((n < 2048) ? wk : wv);
  o[t] = f32_bf16(src[(size_t)k*1024 + (n & 1023)]);
}

__global__ __launch_bounds__(256) void pack_wo_k(const float* __restrict__ wo,
                                                 short* __restrict__ o) {
  int t = blockIdx.x*256 + threadIdx.x;   // 1024*1024 elements
  int n = t >> 10, k = t & 1023;
  o[t] = f32_bf16(wo[(size_t)k*1024 + n]);
}

// ---------------- GEMM: C[M,N] = A[M,K] * Bt[N,K]^T (+residual) ----------------
template<bool ADD_RES>
__global__ __launch_bounds__(256) void gemm_bt(const short* __restrict__ A,
                                               const short* __restrict__ Bt,
                                               short* __restrict__ Cb,
                                               float* __restrict__ Cf,
                                               const float* __restrict__ res,
                                               int M, int N, int K) {
  constexpr int BK = 32;
  __shared__ __align__(16) short As[128*BK];
  __shared__ __align__(16) short Bs[128*BK];
  int tid = threadIdx.x;
  int w = tid >> 6, lane = tid & 63, quad = lane >> 4, l16 = lane & 15;
  int wr = w >> 1, wc = w & 1;
  int bn = blockIdx.x, bm = blockIdx.y;
  const short* Ag = A + (size_t)bm * 128 * K;
  const short* Bg = Bt + (size_t)bn * 128 * K;
  int r4 = lane >> 2, c4 = lane & 3;

  floatx4 acc[4][4] = {};

  for (int k0 = 0; k0 < K; k0 += BK) {
    #pragma unroll
    for (int i = 0; i < 2; i++) {
      int c = w + i*4;
      gload16(Ag + (size_t)(c*16 + r4) * K + k0 + c4*8, &As[c*16*BK]);
      gload16(Bg + (size_t)(c*16 + r4) * K + k0 + c4*8, &Bs[c*16*BK]);
    }
    __syncthreads();
    bf16x8 af[4], bfr[4];
    #pragma unroll
    for (int i = 0; i < 4; i++) {
      af[i]  = *(const bf16x8*)&As[(wr*64 + i*16 + l16)*BK + quad*8];
      bfr[i] = *(const bf16x8*)&Bs[(wc*64 + i*16 + l16)*BK + quad*8];
    }
    #pragma unroll
    for (int i = 0; i < 4; i++)
      #pragma unroll
      for (int j = 0; j < 4; j++)
        acc[i][j] = __builtin_amdgcn_mfma_f32_16x16x32_bf16(af[i], bfr[j], acc[i][j], 0, 0, 0);
    __syncthreads();
  }

  #pragma unroll
  for (int i = 0; i < 4; i++) {
    int row0 = bm*128 + wr*64 + i*16 + quad*4;
    #pragma unroll
    for (int j = 0; j < 4; j++) {
      int col = bn*128 + wc*64 + j*16 + l16;
      #pragma unroll
      for (int r = 0; r < 4; r++) {
        size_t idx = (size_t)(row0 + r) * N + col;
        if (ADD_RES) Cf[idx] = res[idx] + acc[i][j][r];
        else         Cb[idx] = f32_bf16(acc[i][j][r]);
      }
    }
  }
}

// ---------------- V transpose pack: vt[bh][hd][s] ----------------
__global__ __launch_bounds__(256) void pack_vt_k(const short* __restrict__ qkv,
                                                 short* __restrict__ vt) {
  __shared__ __align__(16) short tile[64][72];
  int s0 = blockIdx.x * 64;
  int bh = blockIdx.y;
  int b = bh >> 4, h = bh & 15;
  int t = threadIdx.x;
  #pragma unroll
  for (int i = 0; i < 2; i++) {
    int idx = t + i*256;
    int s = idx >> 3, c = idx & 7;
    *(bf16x8*)&tile[s][c*8] =
      *(const bf16x8*)&qkv[(size_t)(b*S_LEN + s0 + s)*3072 + 2048 + h*64 + c*8];
  }
  __syncthreads();
  #pragma unroll
  for (int i = 0; i < 2; i++) {
    int idx = t + i*256;
    int hd = idx >> 3, c = idx & 7;
    short tmp[8];
    #pragma unroll
    for (int j = 0; j < 8; j++) tmp[j] = tile[c*8 + j][hd];
    *(bf16x8*)&vt[((size_t)(bh*64 + hd))*S_LEN + s0 + c*8] = *(bf16x8*)tmp;
  }
}

// ---------------- Flash attention with T5 relative bias ----------------
__global__ __launch_bounds__(256) void flash_k(const short* __restrict__ qkv,
                                               const short* __restrict__ vt,
                                               const float* __restrict__ rel_emb,
                                               short* __restrict__ ctx) {
  __shared__ __align__(16) short Ks[64*72];
  __shared__ __align__(16) short Vs[64*72];
  __shared__ __align__(16) short Ps[4][16*72];
  __shared__ float lut[129];

  int qt = blockIdx.x, bh = blockIdx.y;
  int b = bh >> 4, h = bh & 15;
  int t = threadIdx.x, w = t >> 6, lane = t & 63, quad = lane >> 4, l16 = lane & 15;

  if (t < 129) {
    int rp = t, bucket;
    if (rp < 16) bucket = rp;
    else {
      bucket = 16 + (int)(logf((float)rp * 0.0625f) * (16.f / logf(8.f)));
      if (bucket > 31) bucket = 31;
    }
    lut[t] = rel_emb[bucket*16 + h];
  }

  int qrow = qt*64 + w*16 + l16;
  const short* qb = qkv + (size_t)(b*S_LEN + qrow)*3072 + h*64;
  bf16x8 qA0 = *(const bf16x8*)&qb[quad*8];
  bf16x8 qA1 = *(const bf16x8*)&qb[32 + quad*8];

  floatx4 o0 = {}, o1 = {}, o2 = {}, o3 = {};
  float mi[4], li[4];
  #pragma unroll
  for (int r = 0; r < 4; r++) { mi[r] = -1e30f; li[r] = 0.f; }

  for (int kt = 0; kt < 32; kt++) {
    int k0 = kt*64;
    #pragma unroll
    for (int i = 0; i < 2; i++) {
      int idx = t + i*256;
      int r = idx >> 3, c = idx & 7;
      *(bf16x8*)&Ks[r*72 + c*8] =
        *(const bf16x8*)&qkv[(size_t)(b*S_LEN + k0 + r)*3072 + 1024 + h*64 + c*8];
      *(bf16x8*)&Vs[r*72 + c*8] =
        *(const bf16x8*)&vt[((size_t)(bh*64 + r))*S_LEN + k0 + c*8];
    }
    __syncthreads();

    floatx4 sc4[4];
    #pragma unroll
    for (int c = 0; c < 4; c++) {
      bf16x8 kb0 = *(const bf16x8*)&Ks[(c*16 + l16)*72 + quad*8];
      bf16x8 kb1 = *(const bf16x8*)&Ks[(c*16 + l16)*72 + 32 + quad*8];
      floatx4 z = {};
      z = __builtin_amdgcn_mfma_f32_16x16x32_bf16(qA0, kb0, z, 0, 0, 0);
      z = __builtin_amdgcn_mfma_f32_16x16x32_bf16(qA1, kb1, z, 0, 0, 0);
      sc4[c] = z;
    }

    int qq0 = qt*64 + w*16 + quad*4;
    #pragma unroll
    for (int c = 0; c < 4; c++) {
      int kk = k0 + c*16 + l16;
      #pragma unroll
      for (int r = 0; r < 4; r++) {
        int d = qq0 + r - kk;
        d = d < 0 ? 0 : (d > 128 ? 128 : d);
        sc4[c][r] += lut[d];
      }
    }

    #pragma unroll
    for (int r = 0; r < 4; r++) {
      float mx = fmaxf(fmaxf(sc4[0][r], sc4[1][r]), fmaxf(sc4[2][r], sc4[3][r]));
      mx = fmaxf(mx, __shfl_xor(mx, 1));
      mx = fmaxf(mx, __shfl_xor(mx, 2));
      mx = fmaxf(mx, __shfl_xor(mx, 4));
      mx = fmaxf(mx, __shfl_xor(mx, 8));
      float mn = fmaxf(mi[r], mx);
      float al = __expf(mi[r] - mn);
      mi[r] = mn;
      li[r] *= al;
      o0[r] *= al; o1[r] *= al; o2[r] *= al; o3[r] *= al;
      float rs = 0.f;
      #pragma unroll
      for (int c = 0; c < 4; c++) {
        float p = __expf(sc4[c][r] - mn);
        sc4[c][r] = p;
        rs += p;
      }
      rs += __shfl_xor(rs, 1); rs += __shfl_xor(rs, 2);
      rs += __shfl_xor(rs, 4); rs += __shfl_xor(rs, 8);
      li[r] += rs;
    }

    short* pw = &Ps[w][0];
    #pragma unroll
    for (int c = 0; c < 4; c++)
      #pragma unroll
      for (int r = 0; r < 4; r++)
        pw[(quad*4 + r)*72 + c*16 + l16] = f32_bf16(sc4[c][r]);

    __syncthreads();

    bf16x8 pa0 = *(const bf16x8*)&pw[l16*72 + quad*8];
    bf16x8 pa1 = *(const bf16x8*)&pw[l16*72 + 32 + quad*8];
    {
      bf16x8 v0a = *(const bf16x8*)&Vs[(0*16 + l16)*72 + quad*8];
      bf16x8 v0b = *(const bf16x8*)&Vs[(0*16 + l16)*72 + 32 + quad*8];
      o0 = __builtin_amdgcn_mfma_f32_16x16x32_bf16(pa0, v0a, o0, 0, 0, 0);
      o0 = __builtin_amdgcn_mfma_f32_16x16x32_bf16(pa1, v0b, o0, 0, 0, 0);
      bf16x8 v1a = *(const bf16x8*)&Vs[(1*16 + l16)*72 + quad*8];
      bf16x8 v1b = *(const bf16x8*)&Vs[(1*16 + l16)*72 + 32 + quad*8];
      o1 = __builtin_amdgcn_mfma_f32_16x16x32_bf16(pa0, v1a, o1, 0, 0, 0);
      o1 = __builtin_amdgcn_mfma_f32_16x16x32_bf16(pa1, v1b, o1, 0, 0, 0);
      bf16x8 v2a = *(const bf16x8*)&Vs[(2*16 + l16)*72 + quad*8];
      bf16x8 v2b = *(const bf16x8*)&Vs[(2*16 + l16)*72 + 32 + quad*8];
      o2 = __builtin_amdgcn_mfma_f32_16x16x32_bf16(pa0, v2a, o2, 0, 0, 0);
      o2 = __builtin_amdgcn_mfma_f32_16x16x32_bf16(pa1, v2b, o2, 0, 0, 0);
      bf16x8 v3a = *(const bf16x8*)&Vs[(3*16 + l16)*72 + quad*8];
      bf16x8 v3b = *(const bf16x8*)&Vs[(3*16 + l16)*72 + 32 + quad*8];
      o3 = __builtin_amdgcn_mfma_f32_16x16x32_bf16(pa0, v3a, o3, 0, 0, 0);
      o3 = __builtin_amdgcn_mfma_f32_16x16x32_bf16(pa1, v3b, o3, 0, 0, 0);
    }
    __syncthreads();
  }

  int qq0 = qt*64 + w*16 + quad*4;
  #pragma unroll
  for (int r = 0; r < 4; r++) {
    float inv = 1.f / li[r];
    size_t base = (size_t)(b*S_LEN + qq0 + r)*1024 + h*64 + l16;
    ctx[base]      = f32_bf16(o0[r]*inv);
    ctx[base + 16] = f32_bf16(o1[r]*inv);
    ctx[base + 32] = f32_bf16(o2[r]*inv);
    ctx[base + 48] = f32_bf16(o3[r]*inv);
  }
}

extern "C" void kernel_launch(void* const* d_in, const int* in_sizes, int n_in,
                              void* d_out, int out_size, void* d_ws, size_t ws_size,
                              hipStream_t stream) {
  const float* input_ids = (const float*)d_in[0];
  // d_in[1] = encoder_output (unused by the reference computation)
  const float* wq      = (const float*)d_in[2];
  const float* wk      = (const float*)d_in[3];
  const float* wv      = (const float*)d_in[4];
  const float* wo      = (const float*)d_in[5];
  const float* rel_emb = (const float*)d_in[6];
  const float* ln_w    = (const float*)d_in[7];
  float* out = (float*)d_out;

  char* ws = (char*)d_ws;
  short* xb     = (short*)ws;  ws += (size_t)8192*1024*2;   // 16 MB
  short* wqkv_t = (short*)ws;  ws += (size_t)3072*1024*2;   // 6 MB
  short* wo_t   = (short*)ws;  ws += (size_t)1024*1024*2;   // 2 MB
  short* qkv    = (short*)ws;  ws += (size_t)8192*3072*2;   // 50 MB
  short* vt     = (short*)ws;  ws += (size_t)64*64*2048*2;  // 16 MB
  short* ctx    = (short*)ws;  ws += (size_t)8192*1024*2;   // 16 MB

  rmsnorm_k<<<8192, 256, 0, stream>>>(input_ids, ln_w, xb);
  pack_wqkv_k<<<(3072*1024)/256, 256, 0, stream>>>(wq, wk, wv, wqkv_t);
  pack_wo_k<<<(1024*1024)/256, 256, 0, stream>>>(wo, wo_t);
  gemm_bt<false><<<dim3(24, 64), 256, 0, stream>>>(xb, wqkv_t, qkv, nullptr, nullptr,
                                                   8192, 3072, 1024);
  pack_vt_k<<<dim3(32, 64), 256, 0, stream>>>(qkv, vt);
  flash_k<<<dim3(32, 64), 256, 0, stream>>>(qkv, vt, rel_emb, ctx);
  gemm_bt<true><<<dim3(8, 64), 256, 0, stream>>>(ctx, wo_t, nullptr, out, input_ids,
                                                 8192, 1024, 1024);
}

// Round 3
// 366.847 us; speedup vs baseline: 1.3327x; 1.3327x over previous
//
#include <hip/hip_runtime.h>
#include <hip/hip_bf16.h>
#include <math.h>

#define S_LEN 2048
#define D_DIM 1024
#define NHEAD 16

typedef __attribute__((ext_vector_type(8))) short bf16x8;
typedef __attribute__((ext_vector_type(4))) float floatx4;

__device__ __forceinline__ short f32_bf16(float f) {
  union { float f; unsigned u; } v; v.f = f;
  unsigned r = v.u + 0x7FFFu + ((v.u >> 16) & 1u);
  return (short)(r >> 16);
}

__device__ __forceinline__ void gload16(const void* g, void* l) {
  __builtin_amdgcn_global_load_lds((const __attribute__((address_space(1))) unsigned*)g,
                                   (__attribute__((address_space(3))) unsigned*)l,
                                   16, 0, 0);
}

// ---------------- RMSNorm (fp32 in -> bf16 out) ----------------
__global__ __launch_bounds__(256) void rmsnorm_k(const float* __restrict__ x,
                                                 const float* __restrict__ w,
                                                 short* __restrict__ out) {
  int row = blockIdx.x;
  const float4* xr = (const float4*)(x + (size_t)row * D_DIM);
  float4 v = xr[threadIdx.x];
  float ss = v.x*v.x + v.y*v.y + v.z*v.z + v.w*v.w;
  #pragma unroll
  for (int off = 32; off > 0; off >>= 1) ss += __shfl_xor(ss, off);
  __shared__ float red[4];
  if ((threadIdx.x & 63) == 0) red[threadIdx.x >> 6] = ss;
  __syncthreads();
  float scale = rsqrtf((red[0]+red[1]+red[2]+red[3]) * (1.f/D_DIM) + 1e-6f);
  float4 wv = ((const float4*)w)[threadIdx.x];
  short4 o;
  o.x = f32_bf16(v.x*scale*wv.x);
  o.y = f32_bf16(v.y*scale*wv.y);
  o.z = f32_bf16(v.z*scale*wv.z);
  o.w = f32_bf16(v.w*scale*wv.w);
  ((short4*)out)[(size_t)row*256 + threadIdx.x] = o;
}

// ---------------- weight repack: B^T layout, bf16 ----------------
__global__ __launch_bounds__(256) void pack_wqkv_k(const float* __restrict__ wq,
                                                   const float* __restrict__ wk,
                                                   const float* __restrict__ wv,
                                                   short* __restrict__ o) {
  int t = blockIdx.x*256 + threadIdx.x;   // 3072*1024 elements
  int n = t >> 10, k = t & 1023;
  const float* src = (n < 1024) ? wq : ((n < 2048) ? wk : wv);
  o[t] = f32_bf16(src[(size_t)k*1024 + (n & 1023)]);
}

__global__ __launch_bounds__(256) void pack_wo_k(const float* __restrict__ wo,
                                                 short* __restrict__ o) {
  int t = blockIdx.x*256 + threadIdx.x;   // 1024*1024 elements
  int n = t >> 10, k = t & 1023;
  o[t] = f32_bf16(wo[(size_t)k*1024 + n]);
}

// ---------------- GEMM: C[M,N] = A[M,K] * Bt[N,K]^T (+residual) ----------------
template<bool ADD_RES>
__global__ __launch_bounds__(256) void gemm_bt(const short* __restrict__ A,
                                               const short* __restrict__ Bt,
                                               short* __restrict__ Cb,
                                               float* __restrict__ Cf,
                                               const float* __restrict__ res,
                                               int M, int N, int K) {
  constexpr int BK = 32;
  __shared__ __align__(16) short As[128*BK];
  __shared__ __align__(16) short Bs[128*BK];
  int tid = threadIdx.x;
  int w = tid >> 6, lane = tid & 63, quad = lane >> 4, l16 = lane & 15;
  int wr = w >> 1, wc = w & 1;
  int bn = blockIdx.x, bm = blockIdx.y;
  const short* Ag = A + (size_t)bm * 128 * K;
  const short* Bg = Bt + (size_t)bn * 128 * K;
  int r4 = lane >> 2, c4 = lane & 3;

  floatx4 acc[4][4] = {};

  for (int k0 = 0; k0 < K; k0 += BK) {
    #pragma unroll
    for (int i = 0; i < 2; i++) {
      int c = w + i*4;
      gload16(Ag + (size_t)(c*16 + r4) * K + k0 + c4*8, &As[c*16*BK]);
      gload16(Bg + (size_t)(c*16 + r4) * K + k0 + c4*8, &Bs[c*16*BK]);
    }
    __syncthreads();
    bf16x8 af[4], bfr[4];
    #pragma unroll
    for (int i = 0; i < 4; i++) {
      af[i]  = *(const bf16x8*)&As[(wr*64 + i*16 + l16)*BK + quad*8];
      bfr[i] = *(const bf16x8*)&Bs[(wc*64 + i*16 + l16)*BK + quad*8];
    }
    #pragma unroll
    for (int i = 0; i < 4; i++)
      #pragma unroll
      for (int j = 0; j < 4; j++)
        acc[i][j] = __builtin_amdgcn_mfma_f32_16x16x32_bf16(af[i], bfr[j], acc[i][j], 0, 0, 0);
    __syncthreads();
  }

  #pragma unroll
  for (int i = 0; i < 4; i++) {
    int row0 = bm*128 + wr*64 + i*16 + quad*4;
    #pragma unroll
    for (int j = 0; j < 4; j++) {
      int col = bn*128 + wc*64 + j*16 + l16;
      #pragma unroll
      for (int r = 0; r < 4; r++) {
        size_t idx = (size_t)(row0 + r) * N + col;
        if (ADD_RES) Cf[idx] = res[idx] + acc[i][j][r];
        else         Cb[idx] = f32_bf16(acc[i][j][r]);
      }
    }
  }
}

// ---------------- V transpose pack: vt[bh][hd][s] ----------------
__global__ __launch_bounds__(256) void pack_vt_k(const short* __restrict__ qkv,
                                                 short* __restrict__ vt) {
  __shared__ __align__(16) short tile[64][72];
  int s0 = blockIdx.x * 64;
  int bh = blockIdx.y;
  int b = bh >> 4, h = bh & 15;
  int t = threadIdx.x;
  #pragma unroll
  for (int i = 0; i < 2; i++) {
    int idx = t + i*256;
    int s = idx >> 3, c = idx & 7;
    *(bf16x8*)&tile[s][c*8] =
      *(const bf16x8*)&qkv[(size_t)(b*S_LEN + s0 + s)*3072 + 2048 + h*64 + c*8];
  }
  __syncthreads();
  #pragma unroll
  for (int i = 0; i < 2; i++) {
    int idx = t + i*256;
    int hd = idx >> 3, c = idx & 7;
    short tmp[8];
    #pragma unroll
    for (int j = 0; j < 8; j++) tmp[j] = tile[c*8 + j][hd];
    *(bf16x8*)&vt[((size_t)(bh*64 + hd))*S_LEN + s0 + c*8] = *(bf16x8*)tmp;
  }
}

// ---------------- Flash attention v2: no-max softmax, const-bias fast path,
// gload16 double-buffered K/V (XOR chunk swizzle), one barrier per k-tile ----
__global__ __launch_bounds__(256) void flash_k(const short* __restrict__ qkv,
                                               const short* __restrict__ vt,
                                               const float* __restrict__ rel_emb,
                                               short* __restrict__ ctx) {
  __shared__ __align__(16) short Kb[2][64*64];   // unpadded, XOR-swizzled chunks
  __shared__ __align__(16) short Vb[2][64*64];
  __shared__ __align__(16) short Ps[4][32*72];   // wave-private P tiles
  __shared__ float lut2[132];                    // bias * log2(e)

  const int qt = blockIdx.x, bh = blockIdx.y;
  const int b = bh >> 4, h = bh & 15;
  const int t = threadIdx.x, w = t >> 6, lane = t & 63, quad = lane >> 4, l16 = lane & 15;
  const float L2E = 1.44269504f;

  if (t < 129) {
    int rp = t, bucket;
    if (rp < 16) bucket = rp;
    else {
      bucket = 16 + (int)(logf((float)rp * 0.0625f) * (16.f / logf(8.f)));
      if (bucket > 31) bucket = 31;
    }
    lut2[t] = rel_emb[bucket*16 + h] * L2E;
  }
  const float bfut  = rel_emb[h] * L2E;            // d <= 0  -> bucket 0
  const float bpast = rel_emb[31*16 + h] * L2E;    // d >= 128 -> bucket 31

  // staging: wave w covers rows [w*16, w*16+16); per-issue 8 rows; lane L:
  // row = base + (L>>3), phys chunk = L&7 holds logical chunk (L&7)^(L>>3)
  const int srow = lane >> 3;
  const int slc  = (lane & 7) ^ srow;

  // Q fragments (A-layout, registers)
  bf16x8 qA[2][2];
  #pragma unroll
  for (int rb = 0; rb < 2; rb++) {
    const short* qb = qkv + ((size_t)(b*S_LEN + qt*128 + rb*64 + w*16 + l16))*3072 + h*64;
    qA[rb][0] = *(const bf16x8*)&qb[quad*8];
    qA[rb][1] = *(const bf16x8*)&qb[32 + quad*8];
  }

  floatx4 o[2][4] = {};
  floatx4 li4[2] = {};
  short one_s = (l16 == 0) ? (short)0x3F80 : (short)0;
  bf16x8 onesf = {one_s, one_s, one_s, one_s, one_s, one_s, one_s, one_s};

  const int swz0 = (quad     ^ (l16 & 7)) * 8;
  const int swz1 = ((quad+4) ^ (l16 & 7)) * 8;

  // stage k-tile kt into buffer p
  #define STAGE(p_, kt_) do {                                                   \
    int r_ = w*16 + srow;                                                       \
    const short* kg_ = qkv + ((size_t)(b*S_LEN + (kt_)*64 + r_))*3072 + 1024 + h*64 + slc*8; \
    gload16(kg_,            &Kb[p_][(w*16    )*64]);                            \
    gload16(kg_ + 8*3072,   &Kb[p_][(w*16 + 8)*64]);                            \
    const short* vg_ = vt + ((size_t)(bh*64 + r_))*2048 + (kt_)*64 + slc*8;     \
    gload16(vg_,            &Vb[p_][(w*16    )*64]);                            \
    gload16(vg_ + 8*2048,   &Vb[p_][(w*16 + 8)*64]);                            \
  } while (0)

  STAGE(0, 0);
  int p = 0;
  short* pw = &Ps[w][0];

  for (int kt = 0; kt < 32; kt++) {
    __syncthreads();   // buffer p staged; lut2 ready (kt==0)

    // ---- QK^T ----
    floatx4 sc[2][4];
    #pragma unroll
    for (int c = 0; c < 4; c++) {
      int rowB = (c*16 + l16)*64;
      bf16x8 kb0 = *(const bf16x8*)&Kb[p][rowB + swz0];
      bf16x8 kb1 = *(const bf16x8*)&Kb[p][rowB + swz1];
      #pragma unroll
      for (int rb = 0; rb < 2; rb++) {
        floatx4 z = {};
        z = __builtin_amdgcn_mfma_f32_16x16x32_bf16(qA[rb][0], kb0, z, 0, 0, 0);
        z = __builtin_amdgcn_mfma_f32_16x16x32_bf16(qA[rb][1], kb1, z, 0, 0, 0);
        sc[rb][c] = z;
      }
    }

    // ---- bias + exp (no running max) + pack P (truncate) ----
    bool boundary = (kt >= 2*qt - 2) && (kt <= 2*qt + 1);
    if (boundary) {
      #pragma unroll
      for (int rb = 0; rb < 2; rb++) {
        int q0 = qt*128 + rb*64 + w*16 + quad*4;
        #pragma unroll
        for (int c = 0; c < 4; c++) {
          int kk = kt*64 + c*16 + l16;
          #pragma unroll
          for (int r = 0; r < 4; r++) {
            int d = q0 + r - kk;
            d = d < 0 ? 0 : (d > 128 ? 128 : d);
            float pv = exp2f(fmaf(sc[rb][c][r], L2E, lut2[d]));
            pw[(rb*16 + quad*4 + r)*72 + c*16 + l16] =
              (short)(__float_as_uint(pv) >> 16);
          }
        }
      }
    } else {
      float bconst = (kt >= 2*qt) ? bfut : bpast;
      #pragma unroll
      for (int rb = 0; rb < 2; rb++)
        #pragma unroll
        for (int c = 0; c < 4; c++)
          #pragma unroll
          for (int r = 0; r < 4; r++) {
            float pv = exp2f(fmaf(sc[rb][c][r], L2E, bconst));
            pw[(rb*16 + quad*4 + r)*72 + c*16 + l16] =
              (short)(__float_as_uint(pv) >> 16);
          }
    }

    // prefetch next k-tile into the other buffer (drained at next barrier)
    if (kt < 31) STAGE(p^1, kt+1);

    // ---- PV + row-sum (ones-column MFMA) ----
    #pragma unroll
    for (int rb = 0; rb < 2; rb++) {
      bf16x8 pa0 = *(const bf16x8*)&pw[(rb*16 + l16)*72 + quad*8];
      bf16x8 pa1 = *(const bf16x8*)&pw[(rb*16 + l16)*72 + 32 + quad*8];
      li4[rb] = __builtin_amdgcn_mfma_f32_16x16x32_bf16(pa0, onesf, li4[rb], 0, 0, 0);
      li4[rb] = __builtin_amdgcn_mfma_f32_16x16x32_bf16(pa1, onesf, li4[rb], 0, 0, 0);
      #pragma unroll
      for (int jj = 0; jj < 4; jj++) {
        int rowV = (jj*16 + l16)*64;
        bf16x8 vb0 = *(const bf16x8*)&Vb[p][rowV + swz0];
        bf16x8 vb1 = *(const bf16x8*)&Vb[p][rowV + swz1];
        o[rb][jj] = __builtin_amdgcn_mfma_f32_16x16x32_bf16(pa0, vb0, o[rb][jj], 0, 0, 0);
        o[rb][jj] = __builtin_amdgcn_mfma_f32_16x16x32_bf16(pa1, vb1, o[rb][jj], 0, 0, 0);
      }
    }
    p ^= 1;
  }

  // ---- epilogue: normalize and store ----
  #pragma unroll
  for (int rb = 0; rb < 2; rb++) {
    float inv[4];
    #pragma unroll
    for (int r = 0; r < 4; r++) {
      float lsum = __shfl(li4[rb][r], lane & 48, 64);  // broadcast from l16==0 lane
      inv[r] = 1.f / lsum;
    }
    #pragma unroll
    for (int jj = 0; jj < 4; jj++)
      #pragma unroll
      for (int r = 0; r < 4; r++) {
        size_t row = (size_t)(b*S_LEN + qt*128 + rb*64 + w*16 + quad*4 + r);
        ctx[row*1024 + h*64 + jj*16 + l16] = f32_bf16(o[rb][jj][r] * inv[r]);
      }
  }
  #undef STAGE
}

extern "C" void kernel_launch(void* const* d_in, const int* in_sizes, int n_in,
                              void* d_out, int out_size, void* d_ws, size_t ws_size,
                              hipStream_t stream) {
  const float* input_ids = (const float*)d_in[0];
  // d_in[1] = encoder_output (unused by the reference computation)
  const float* wq      = (const float*)d_in[2];
  const float* wk      = (const float*)d_in[3];
  const float* wv      = (const float*)d_in[4];
  const float* wo      = (const float*)d_in[5];
  const float* rel_emb = (const float*)d_in[6];
  const float* ln_w    = (const float*)d_in[7];
  float* out = (float*)d_out;

  char* ws = (char*)d_ws;
  short* xb     = (short*)ws;  ws += (size_t)8192*1024*2;   // 16 MB
  short* wqkv_t = (short*)ws;  ws += (size_t)3072*1024*2;   // 6 MB
  short* wo_t   = (short*)ws;  ws += (size_t)1024*1024*2;   // 2 MB
  short* qkv    = (short*)ws;  ws += (size_t)8192*3072*2;   // 50 MB
  short* vt     = (short*)ws;  ws += (size_t)64*64*2048*2;  // 16 MB
  short* ctx    = (short*)ws;  ws += (size_t)8192*1024*2;   // 16 MB

  rmsnorm_k<<<8192, 256, 0, stream>>>(input_ids, ln_w, xb);
  pack_wqkv_k<<<(3072*1024)/256, 256, 0, stream>>>(wq, wk, wv, wqkv_t);
  pack_wo_k<<<(1024*1024)/256, 256, 0, stream>>>(wo, wo_t);
  gemm_bt<false><<<dim3(24, 64), 256, 0, stream>>>(xb, wqkv_t, qkv, nullptr, nullptr,
                                                   8192, 3072, 1024);
  pack_vt_k<<<dim3(32, 64), 256, 0, stream>>>(qkv, vt);
  flash_k<<<dim3(16, 64), 256, 0, stream>>>(qkv, vt, rel_emb, ctx);
  gemm_bt<true><<<dim3(8, 64), 256, 0, stream>>>(ctx, wo_t, nullptr, out, input_ids,
                                                 8192, 1024, 1024);
}

// Round 4
// 351.541 us; speedup vs baseline: 1.3907x; 1.0435x over previous
//
#include <hip/hip_runtime.h>
#include <hip/hip_bf16.h>
#include <math.h>

#define S_LEN 2048
#define D_DIM 1024
#define NHEAD 16

typedef __attribute__((ext_vector_type(8))) short bf16x8;
typedef __attribute__((ext_vector_type(4))) float floatx4;

__device__ __forceinline__ short f32_bf16(float f) {
  union { float f; unsigned u; } v; v.f = f;
  unsigned r = v.u + 0x7FFFu + ((v.u >> 16) & 1u);
  return (short)(r >> 16);
}

__device__ __forceinline__ void gload16(const void* g, void* l) {
  __builtin_amdgcn_global_load_lds((const __attribute__((address_space(1))) unsigned*)g,
                                   (__attribute__((address_space(3))) unsigned*)l,
                                   16, 0, 0);
}

// ---------------- RMSNorm (fp32 in -> bf16 out) ----------------
__global__ __launch_bounds__(256) void rmsnorm_k(const float* __restrict__ x,
                                                 const float* __restrict__ w,
                                                 short* __restrict__ out) {
  int row = blockIdx.x;
  const float4* xr = (const float4*)(x + (size_t)row * D_DIM);
  float4 v = xr[threadIdx.x];
  float ss = v.x*v.x + v.y*v.y + v.z*v.z + v.w*v.w;
  #pragma unroll
  for (int off = 32; off > 0; off >>= 1) ss += __shfl_xor(ss, off);
  __shared__ float red[4];
  if ((threadIdx.x & 63) == 0) red[threadIdx.x >> 6] = ss;
  __syncthreads();
  float scale = rsqrtf((red[0]+red[1]+red[2]+red[3]) * (1.f/D_DIM) + 1e-6f);
  float4 wv = ((const float4*)w)[threadIdx.x];
  short4 o;
  o.x = f32_bf16(v.x*scale*wv.x);
  o.y = f32_bf16(v.y*scale*wv.y);
  o.z = f32_bf16(v.z*scale*wv.z);
  o.w = f32_bf16(v.w*scale*wv.w);
  ((short4*)out)[(size_t)row*256 + threadIdx.x] = o;
}

// ---------------- weight repack: B^T layout, bf16 ----------------
__global__ __launch_bounds__(256) void pack_wqkv_k(const float* __restrict__ wq,
                                                   const float* __restrict__ wk,
                                                   const float* __restrict__ wv,
                                                   short* __restrict__ o) {
  int t = blockIdx.x*256 + threadIdx.x;   // 3072*1024 elements
  int n = t >> 10, k = t & 1023;
  const float* src = (n < 1024) ? wq : ((n < 2048) ? wk : wv);
  o[t] = f32_bf16(src[(size_t)k*1024 + (n & 1023)]);
}

__global__ __launch_bounds__(256) void pack_wo_k(const float* __restrict__ wo,
                                                 short* __restrict__ o) {
  int t = blockIdx.x*256 + threadIdx.x;   // 1024*1024 elements
  int n = t >> 10, k = t & 1023;
  o[t] = f32_bf16(wo[(size_t)k*1024 + n]);
}

// ---------------- GEMM: C[M,N] = A[M,K] * Bt[N,K]^T (+residual) ----------------
template<bool ADD_RES>
__global__ __launch_bounds__(256) void gemm_bt(const short* __restrict__ A,
                                               const short* __restrict__ Bt,
                                               short* __restrict__ Cb,
                                               float* __restrict__ Cf,
                                               const float* __restrict__ res,
                                               int M, int N, int K) {
  constexpr int BK = 32;
  __shared__ __align__(16) short As[128*BK];
  __shared__ __align__(16) short Bs[128*BK];
  int tid = threadIdx.x;
  int w = tid >> 6, lane = tid & 63, quad = lane >> 4, l16 = lane & 15;
  int wr = w >> 1, wc = w & 1;
  int bn = blockIdx.x, bm = blockIdx.y;
  const short* Ag = A + (size_t)bm * 128 * K;
  const short* Bg = Bt + (size_t)bn * 128 * K;
  int r4 = lane >> 2, c4 = lane & 3;

  floatx4 acc[4][4] = {};

  for (int k0 = 0; k0 < K; k0 += BK) {
    #pragma unroll
    for (int i = 0; i < 2; i++) {
      int c = w + i*4;
      gload16(Ag + (size_t)(c*16 + r4) * K + k0 + c4*8, &As[c*16*BK]);
      gload16(Bg + (size_t)(c*16 + r4) * K + k0 + c4*8, &Bs[c*16*BK]);
    }
    __syncthreads();
    bf16x8 af[4], bfr[4];
    #pragma unroll
    for (int i = 0; i < 4; i++) {
      af[i]  = *(const bf16x8*)&As[(wr*64 + i*16 + l16)*BK + quad*8];
      bfr[i] = *(const bf16x8*)&Bs[(wc*64 + i*16 + l16)*BK + quad*8];
    }
    #pragma unroll
    for (int i = 0; i < 4; i++)
      #pragma unroll
      for (int j = 0; j < 4; j++)
        acc[i][j] = __builtin_amdgcn_mfma_f32_16x16x32_bf16(af[i], bfr[j], acc[i][j], 0, 0, 0);
    __syncthreads();
  }

  #pragma unroll
  for (int i = 0; i < 4; i++) {
    int row0 = bm*128 + wr*64 + i*16 + quad*4;
    #pragma unroll
    for (int j = 0; j < 4; j++) {
      int col = bn*128 + wc*64 + j*16 + l16;
      #pragma unroll
      for (int r = 0; r < 4; r++) {
        size_t idx = (size_t)(row0 + r) * N + col;
        if (ADD_RES) Cf[idx] = res[idx] + acc[i][j][r];
        else         Cb[idx] = f32_bf16(acc[i][j][r]);
      }
    }
  }
}

// ---------------- V transpose pack: vt[bh][hd][s] ----------------
__global__ __launch_bounds__(256) void pack_vt_k(const short* __restrict__ qkv,
                                                 short* __restrict__ vt) {
  __shared__ __align__(16) short tile[64][72];
  int s0 = blockIdx.x * 64;
  int bh = blockIdx.y;
  int b = bh >> 4, h = bh & 15;
  int t = threadIdx.x;
  #pragma unroll
  for (int i = 0; i < 2; i++) {
    int idx = t + i*256;
    int s = idx >> 3, c = idx & 7;
    *(bf16x8*)&tile[s][c*8] =
      *(const bf16x8*)&qkv[(size_t)(b*S_LEN + s0 + s)*3072 + 2048 + h*64 + c*8];
  }
  __syncthreads();
  #pragma unroll
  for (int i = 0; i < 2; i++) {
    int idx = t + i*256;
    int hd = idx >> 3, c = idx & 7;
    short tmp[8];
    #pragma unroll
    for (int j = 0; j < 8; j++) tmp[j] = tile[c*8 + j][hd];
    *(bf16x8*)&vt[((size_t)(bh*64 + hd))*S_LEN + s0 + c*8] = *(bf16x8*)tmp;
  }
}

// ---------------- Flash attention v3: transposed-score structure.
// S^T = mfma(A=K, B=Q): query lands on l16, key on reg dim. K rows are staged
// into LDS in permuted order pi(16c+4q+r) = 32*(c>>1)+8q+4*(c&1)+r so the
// exp'd scores repack IN REGISTERS (v_perm) into B-fragments of
// O^T = mfma(A=V^T, B=P^T). No P LDS round-trip, no softmax shuffles.
__global__ __launch_bounds__(256) void flash_k(const short* __restrict__ qkv,
                                               const short* __restrict__ vt,
                                               const float* __restrict__ rel_emb,
                                               short* __restrict__ ctx) {
  __shared__ __align__(16) short Kb[2][64*64];   // rows = permuted keys, cols = d
  __shared__ __align__(16) short Vb[2][64*64];   // rows = hd, cols = keys (natural)
  __shared__ float lut2[132];                    // bias * log2(e)

  const int qt = blockIdx.x, bh = blockIdx.y;
  const int b = bh >> 4, h = bh & 15;
  const int t = threadIdx.x, w = t >> 6, lane = t & 63, quad = lane >> 4, l16 = lane & 15;
  const float L2E = 1.44269504f;

  if (t < 129) {
    int rp = t, bucket;
    if (rp < 16) bucket = rp;
    else {
      bucket = 16 + (int)(logf((float)rp * 0.0625f) * (16.f / logf(8.f)));
      if (bucket > 31) bucket = 31;
    }
    lut2[t] = rel_emb[bucket*16 + h] * L2E;
  }
  const float bfut  = rel_emb[h] * L2E;            // d <= 0  -> bucket 0
  const float bpast = rel_emb[31*16 + h] * L2E;    // d >= 128 -> bucket 31

  // staging lane mapping: LDS row = w*16 + srow (+8 for 2nd issue), phys chunk
  // L&7 holds logical chunk slc = (L&7)^srow  (XOR swizzle, row&7 = srow)
  const int srow = lane >> 3;
  const int slc  = (lane & 7) ^ srow;
  // permuted key for K-tile LDS row w*16+srow: key = 32*(w>>1)+8*(srow>>2)+4*(w&1)+(srow&3)
  const int kperm = 32*(w >> 1) + 8*(srow >> 2) + 4*(w & 1) + (srow & 3);

  // Q fragments: lane l16 = query (B-operand n-dim), elems = d (quad*8+j)
  bf16x8 qB[2][2];
  #pragma unroll
  for (int rb = 0; rb < 2; rb++) {
    const short* qb = qkv + ((size_t)(b*S_LEN + qt*128 + rb*64 + w*16 + l16))*3072 + h*64;
    qB[rb][0] = *(const bf16x8*)&qb[quad*8];
    qB[rb][1] = *(const bf16x8*)&qb[32 + quad*8];
  }

  floatx4 o[2][4] = {};      // O^T accumulators: row=d(quad*4+r), col=query(l16)
  floatx4 li4[2] = {};       // row sums per query (all r identical)
  const short ONE = (short)0x3F80;
  bf16x8 onesA = {ONE, ONE, ONE, ONE, ONE, ONE, ONE, ONE};

  const int swz0 = (quad     ^ (l16 & 7)) * 8;
  const int swz1 = ((quad+4) ^ (l16 & 7)) * 8;

  #define STAGE(p_, kt_) do {                                                   \
    const short* kg_ = qkv + ((size_t)(b*S_LEN + (kt_)*64 + kperm))*3072 + 1024 + h*64 + slc*8; \
    gload16(kg_,            &Kb[p_][(w*16    )*64]);                            \
    gload16(kg_ + 16*3072,  &Kb[p_][(w*16 + 8)*64]);                            \
    const short* vg_ = vt + ((size_t)(bh*64 + w*16 + srow))*2048 + (kt_)*64 + slc*8; \
    gload16(vg_,            &Vb[p_][(w*16    )*64]);                            \
    gload16(vg_ + 8*2048,   &Vb[p_][(w*16 + 8)*64]);                            \
  } while (0)

  STAGE(0, 0);
  int p = 0;

  for (int kt = 0; kt < 32; kt++) {
    __syncthreads();   // buffer p staged; lut2 ready (kt==0)

    // ---- S^T = K · Q^T : A-frag rows = permuted key tiles, B = Q ----
    floatx4 sc[2][4];
    #pragma unroll
    for (int c = 0; c < 4; c++) {
      int rowA = (c*16 + l16)*64;
      bf16x8 ka0 = *(const bf16x8*)&Kb[p][rowA + swz0];
      bf16x8 ka1 = *(const bf16x8*)&Kb[p][rowA + swz1];
      #pragma unroll
      for (int rb = 0; rb < 2; rb++) {
        floatx4 z = {};
        z = __builtin_amdgcn_mfma_f32_16x16x32_bf16(ka0, qB[rb][0], z, 0, 0, 0);
        z = __builtin_amdgcn_mfma_f32_16x16x32_bf16(ka1, qB[rb][1], z, 0, 0, 0);
        sc[rb][c] = z;
      }
    }

    // ---- bias + exp in registers (no running max) ----
    bool boundary = (kt >= 2*qt - 2) && (kt <= 2*qt + 1);
    if (boundary) {
      #pragma unroll
      for (int rb = 0; rb < 2; rb++) {
        int q0 = qt*128 + rb*64 + w*16 + l16;
        #pragma unroll
        for (int c = 0; c < 4; c++) {
          // actual key for reg (c,r): kt*64 + 32*(c>>1) + 8*quad + 4*(c&1) + r
          int kk = kt*64 + 32*(c >> 1) + 8*quad + 4*(c & 1);
          #pragma unroll
          for (int r = 0; r < 4; r++) {
            int d = q0 - (kk + r);
            d = d < 0 ? 0 : (d > 128 ? 128 : d);
            sc[rb][c][r] = exp2f(fmaf(sc[rb][c][r], L2E, lut2[d]));
          }
        }
      }
    } else {
      float bconst = (kt >= 2*qt) ? bfut : bpast;
      #pragma unroll
      for (int rb = 0; rb < 2; rb++)
        #pragma unroll
        for (int c = 0; c < 4; c++)
          #pragma unroll
          for (int r = 0; r < 4; r++)
            sc[rb][c][r] = exp2f(fmaf(sc[rb][c][r], L2E, bconst));
    }

    // prefetch next k-tile into the other buffer
    if (kt < 31) STAGE(p^1, kt+1);

    // ---- repack P^T into B-fragments in registers (v_perm hi16 pairs) ----
    bf16x8 pf[2][2];
    #pragma unroll
    for (int rb = 0; rb < 2; rb++) {
      #pragma unroll
      for (int hh = 0; hh < 2; hh++) {
        union { bf16x8 v; unsigned u[4]; } pk;
        floatx4 a = sc[rb][2*hh], bb = sc[rb][2*hh + 1];
        pk.u[0] = __builtin_amdgcn_perm(__float_as_uint(a[1]),  __float_as_uint(a[0]),  0x07060302);
        pk.u[1] = __builtin_amdgcn_perm(__float_as_uint(a[3]),  __float_as_uint(a[2]),  0x07060302);
        pk.u[2] = __builtin_amdgcn_perm(__float_as_uint(bb[1]), __float_as_uint(bb[0]), 0x07060302);
        pk.u[3] = __builtin_amdgcn_perm(__float_as_uint(bb[3]), __float_as_uint(bb[2]), 0x07060302);
        pf[rb][hh] = pk.v;
      }
    }

    // ---- O^T += V^T · P^T ; row-sums via ones-A MFMA ----
    #pragma unroll
    for (int rb = 0; rb < 2; rb++) {
      li4[rb] = __builtin_amdgcn_mfma_f32_16x16x32_bf16(onesA, pf[rb][0], li4[rb], 0, 0, 0);
      li4[rb] = __builtin_amdgcn_mfma_f32_16x16x32_bf16(onesA, pf[rb][1], li4[rb], 0, 0, 0);
      #pragma unroll
      for (int jj = 0; jj < 4; jj++) {
        int rowV = (jj*16 + l16)*64;
        bf16x8 va0 = *(const bf16x8*)&Vb[p][rowV + swz0];
        bf16x8 va1 = *(const bf16x8*)&Vb[p][rowV + swz1];
        o[rb][jj] = __builtin_amdgcn_mfma_f32_16x16x32_bf16(va0, pf[rb][0], o[rb][jj], 0, 0, 0);
        o[rb][jj] = __builtin_amdgcn_mfma_f32_16x16x32_bf16(va1, pf[rb][1], o[rb][jj], 0, 0, 0);
      }
    }
    p ^= 1;
  }

  // ---- epilogue: normalize (per-query sum is lane-local) and store ----
  #pragma unroll
  for (int rb = 0; rb < 2; rb++) {
    float inv = 1.f / li4[rb][0];
    size_t row = (size_t)(b*S_LEN + qt*128 + rb*64 + w*16 + l16);
    #pragma unroll
    for (int jj = 0; jj < 4; jj++) {
      short4 st;
      st.x = f32_bf16(o[rb][jj][0] * inv);
      st.y = f32_bf16(o[rb][jj][1] * inv);
      st.z = f32_bf16(o[rb][jj][2] * inv);
      st.w = f32_bf16(o[rb][jj][3] * inv);
      *(short4*)&ctx[row*1024 + h*64 + jj*16 + quad*4] = st;
    }
  }
  #undef STAGE
}

extern "C" void kernel_launch(void* const* d_in, const int* in_sizes, int n_in,
                              void* d_out, int out_size, void* d_ws, size_t ws_size,
                              hipStream_t stream) {
  const float* input_ids = (const float*)d_in[0];
  // d_in[1] = encoder_output (unused by the reference computation)
  const float* wq      = (const float*)d_in[2];
  const float* wk      = (const float*)d_in[3];
  const float* wv      = (const float*)d_in[4];
  const float* wo      = (const float*)d_in[5];
  const float* rel_emb = (const float*)d_in[6];
  const float* ln_w    = (const float*)d_in[7];
  float* out = (float*)d_out;

  char* ws = (char*)d_ws;
  short* xb     = (short*)ws;  ws += (size_t)8192*1024*2;   // 16 MB
  short* wqkv_t = (short*)ws;  ws += (size_t)3072*1024*2;   // 6 MB
  short* wo_t   = (short*)ws;  ws += (size_t)1024*1024*2;   // 2 MB
  short* qkv    = (short*)ws;  ws += (size_t)8192*3072*2;   // 50 MB
  short* vt     = (short*)ws;  ws += (size_t)64*64*2048*2;  // 16 MB
  short* ctx    = (short*)ws;  ws += (size_t)8192*1024*2;   // 16 MB

  rmsnorm_k<<<8192, 256, 0, stream>>>(input_ids, ln_w, xb);
  pack_wqkv_k<<<(3072*1024)/256, 256, 0, stream>>>(wq, wk, wv, wqkv_t);
  pack_wo_k<<<(1024*1024)/256, 256, 0, stream>>>(wo, wo_t);
  gemm_bt<false><<<dim3(24, 64), 256, 0, stream>>>(xb, wqkv_t, qkv, nullptr, nullptr,
                                                   8192, 3072, 1024);
  pack_vt_k<<<dim3(32, 64), 256, 0, stream>>>(qkv, vt);
  flash_k<<<dim3(16, 64), 256, 0, stream>>>(qkv, vt, rel_emb, ctx);
  gemm_bt<true><<<dim3(8, 64), 256, 0, stream>>>(ctx, wo_t, nullptr, out, input_ids,
                                                 8192, 1024, 1024);
}

// Round 5
// 328.236 us; speedup vs baseline: 1.4894x; 1.0710x over previous
//
#include <hip/hip_runtime.h>
#include <hip/hip_bf16.h>
#include <math.h>

#define S_LEN 2048
#define D_DIM 1024
#define NHEAD 16

typedef __attribute__((ext_vector_type(8))) short bf16x8;
typedef __attribute__((ext_vector_type(4))) float floatx4;

__device__ __forceinline__ short f32_bf16(float f) {
  union { float f; unsigned u; } v; v.f = f;
  unsigned r = v.u + 0x7FFFu + ((v.u >> 16) & 1u);
  return (short)(r >> 16);
}

__device__ __forceinline__ float exp2_fast(float x) {
#if __has_builtin(__builtin_amdgcn_exp2f)
  return __builtin_amdgcn_exp2f(x);
#else
  float r; asm("v_exp_f32 %0, %1" : "=v"(r) : "v"(x)); return r;
#endif
}

__device__ __forceinline__ void gload16(const void* g, void* l) {
  __builtin_amdgcn_global_load_lds((const __attribute__((address_space(1))) unsigned*)g,
                                   (__attribute__((address_space(3))) unsigned*)l,
                                   16, 0, 0);
}

// ---------------- RMSNorm (fp32 in -> bf16 out) ----------------
__global__ __launch_bounds__(256) void rmsnorm_k(const float* __restrict__ x,
                                                 const float* __restrict__ w,
                                                 short* __restrict__ out) {
  int row = blockIdx.x;
  const float4* xr = (const float4*)(x + (size_t)row * D_DIM);
  float4 v = xr[threadIdx.x];
  float ss = v.x*v.x + v.y*v.y + v.z*v.z + v.w*v.w;
  #pragma unroll
  for (int off = 32; off > 0; off >>= 1) ss += __shfl_xor(ss, off);
  __shared__ float red[4];
  if ((threadIdx.x & 63) == 0) red[threadIdx.x >> 6] = ss;
  __syncthreads();
  float scale = rsqrtf((red[0]+red[1]+red[2]+red[3]) * (1.f/D_DIM) + 1e-6f);
  float4 wv = ((const float4*)w)[threadIdx.x];
  short4 o;
  o.x = f32_bf16(v.x*scale*wv.x);
  o.y = f32_bf16(v.y*scale*wv.y);
  o.z = f32_bf16(v.z*scale*wv.z);
  o.w = f32_bf16(v.w*scale*wv.w);
  ((short4*)out)[(size_t)row*256 + threadIdx.x] = o;
}

// ---------------- weight repack: B^T layout, bf16 ----------------
// wq third is pre-scaled by log2(e) so QK^T scores come out in exp2 domain.
__global__ __launch_bounds__(256) void pack_wqkv_k(const float* __restrict__ wq,
                                                   const float* __restrict__ wk,
                                                   const float* __restrict__ wv,
                                                   short* __restrict__ o) {
  int t = blockIdx.x*256 + threadIdx.x;   // 3072*1024 elements
  int n = t >> 10, k = t & 1023;
  const float* src = (n < 1024) ? wq : ((n < 2048) ? wk : wv);
  float scale = (n < 1024) ? 1.44269504f : 1.0f;
  o[t] = f32_bf16(src[(size_t)k*1024 + (n & 1023)] * scale);
}

__global__ __launch_bounds__(256) void pack_wo_k(const float* __restrict__ wo,
                                                 short* __restrict__ o) {
  int t = blockIdx.x*256 + threadIdx.x;   // 1024*1024 elements
  int n = t >> 10, k = t & 1023;
  o[t] = f32_bf16(wo[(size_t)k*1024 + n]);
}

// ---------------- GEMM: C[M,N] = A[M,K] * Bt[N,K]^T (+residual) ----------------
template<bool ADD_RES>
__global__ __launch_bounds__(256) void gemm_bt(const short* __restrict__ A,
                                               const short* __restrict__ Bt,
                                               short* __restrict__ Cb,
                                               float* __restrict__ Cf,
                                               const float* __restrict__ res,
                                               int M, int N, int K) {
  constexpr int BK = 32;
  __shared__ __align__(16) short As[128*BK];
  __shared__ __align__(16) short Bs[128*BK];
  int tid = threadIdx.x;
  int w = tid >> 6, lane = tid & 63, quad = lane >> 4, l16 = lane & 15;
  int wr = w >> 1, wc = w & 1;
  int bn = blockIdx.x, bm = blockIdx.y;
  const short* Ag = A + (size_t)bm * 128 * K;
  const short* Bg = Bt + (size_t)bn * 128 * K;
  int r4 = lane >> 2, c4 = lane & 3;

  floatx4 acc[4][4] = {};

  for (int k0 = 0; k0 < K; k0 += BK) {
    #pragma unroll
    for (int i = 0; i < 2; i++) {
      int c = w + i*4;
      gload16(Ag + (size_t)(c*16 + r4) * K + k0 + c4*8, &As[c*16*BK]);
      gload16(Bg + (size_t)(c*16 + r4) * K + k0 + c4*8, &Bs[c*16*BK]);
    }
    __syncthreads();
    bf16x8 af[4], bfr[4];
    #pragma unroll
    for (int i = 0; i < 4; i++) {
      af[i]  = *(const bf16x8*)&As[(wr*64 + i*16 + l16)*BK + quad*8];
      bfr[i] = *(const bf16x8*)&Bs[(wc*64 + i*16 + l16)*BK + quad*8];
    }
    #pragma unroll
    for (int i = 0; i < 4; i++)
      #pragma unroll
      for (int j = 0; j < 4; j++)
        acc[i][j] = __builtin_amdgcn_mfma_f32_16x16x32_bf16(af[i], bfr[j], acc[i][j], 0, 0, 0);
    __syncthreads();
  }

  #pragma unroll
  for (int i = 0; i < 4; i++) {
    int row0 = bm*128 + wr*64 + i*16 + quad*4;
    #pragma unroll
    for (int j = 0; j < 4; j++) {
      int col = bn*128 + wc*64 + j*16 + l16;
      #pragma unroll
      for (int r = 0; r < 4; r++) {
        size_t idx = (size_t)(row0 + r) * N + col;
        if (ADD_RES) Cf[idx] = res[idx] + acc[i][j][r];
        else         Cb[idx] = f32_bf16(acc[i][j][r]);
      }
    }
  }
}

// ---------------- V transpose pack: vt[bh][hd][s] ----------------
__global__ __launch_bounds__(256) void pack_vt_k(const short* __restrict__ qkv,
                                                 short* __restrict__ vt) {
  __shared__ __align__(16) short tile[64][72];
  int s0 = blockIdx.x * 64;
  int bh = blockIdx.y;
  int b = bh >> 4, h = bh & 15;
  int t = threadIdx.x;
  #pragma unroll
  for (int i = 0; i < 2; i++) {
    int idx = t + i*256;
    int s = idx >> 3, c = idx & 7;
    *(bf16x8*)&tile[s][c*8] =
      *(const bf16x8*)&qkv[(size_t)(b*S_LEN + s0 + s)*3072 + 2048 + h*64 + c*8];
  }
  __syncthreads();
  #pragma unroll
  for (int i = 0; i < 2; i++) {
    int idx = t + i*256;
    int hd = idx >> 3, c = idx & 7;
    short tmp[8];
    #pragma unroll
    for (int j = 0; j < 8; j++) tmp[j] = tile[c*8 + j][hd];
    *(bf16x8*)&vt[((size_t)(bh*64 + hd))*S_LEN + s0 + c*8] = *(bf16x8*)tmp;
  }
}

// ---------------- Flash attention v4: transposed-score structure, bias via
// MFMA C-operand (non-boundary tiles), raw v_exp_f32, Q pre-scaled by log2e.
__global__ __launch_bounds__(256) void flash_k(const short* __restrict__ qkv,
                                               const short* __restrict__ vt,
                                               const float* __restrict__ rel_emb,
                                               short* __restrict__ ctx) {
  __shared__ __align__(16) short Kb[2][64*64];   // rows = permuted keys, cols = d
  __shared__ __align__(16) short Vb[2][64*64];   // rows = hd, cols = keys (natural)
  __shared__ float lut2[132];                    // bias * log2(e)

  const int qt = blockIdx.x, bh = blockIdx.y;
  const int b = bh >> 4, h = bh & 15;
  const int t = threadIdx.x, w = t >> 6, lane = t & 63, quad = lane >> 4, l16 = lane & 15;
  const float L2E = 1.44269504f;

  if (t < 129) {
    int rp = t, bucket;
    if (rp < 16) bucket = rp;
    else {
      bucket = 16 + (int)(logf((float)rp * 0.0625f) * (16.f / logf(8.f)));
      if (bucket > 31) bucket = 31;
    }
    lut2[t] = rel_emb[bucket*16 + h] * L2E;
  }
  const float bfut  = rel_emb[h] * L2E;            // d <= 0  -> bucket 0
  const float bpast = rel_emb[31*16 + h] * L2E;    // d >= 128 -> bucket 31
  const floatx4 bf4 = {bfut, bfut, bfut, bfut};
  const floatx4 bp4 = {bpast, bpast, bpast, bpast};
  const floatx4 zz4 = {0.f, 0.f, 0.f, 0.f};

  const int srow = lane >> 3;
  const int slc  = (lane & 7) ^ srow;
  // permuted key for K-tile LDS row w*16+srow
  const int kperm = 32*(w >> 1) + 8*(srow >> 2) + 4*(w & 1) + (srow & 3);

  // Q fragments: lane l16 = query (B-operand n-dim), elems = d (quad*8+j)
  bf16x8 qB[2][2];
  #pragma unroll
  for (int rb = 0; rb < 2; rb++) {
    const short* qb = qkv + ((size_t)(b*S_LEN + qt*128 + rb*64 + w*16 + l16))*3072 + h*64;
    qB[rb][0] = *(const bf16x8*)&qb[quad*8];
    qB[rb][1] = *(const bf16x8*)&qb[32 + quad*8];
  }

  floatx4 o[2][4] = {};      // O^T accumulators: row=d(quad*4+r), col=query(l16)
  floatx4 li4[2] = {};       // row sums per query
  const short ONE = (short)0x3F80;
  bf16x8 onesA = {ONE, ONE, ONE, ONE, ONE, ONE, ONE, ONE};

  const int swz0 = (quad     ^ (l16 & 7)) * 8;
  const int swz1 = ((quad+4) ^ (l16 & 7)) * 8;

  #define STAGE(p_, kt_) do {                                                   \
    const short* kg_ = qkv + ((size_t)(b*S_LEN + (kt_)*64 + kperm))*3072 + 1024 + h*64 + slc*8; \
    gload16(kg_,            &Kb[p_][(w*16    )*64]);                            \
    gload16(kg_ + 16*3072,  &Kb[p_][(w*16 + 8)*64]);                            \
    const short* vg_ = vt + ((size_t)(bh*64 + w*16 + srow))*2048 + (kt_)*64 + slc*8; \
    gload16(vg_,            &Vb[p_][(w*16    )*64]);                            \
    gload16(vg_ + 8*2048,   &Vb[p_][(w*16 + 8)*64]);                            \
  } while (0)

  STAGE(0, 0);
  int p = 0;

  for (int kt = 0; kt < 32; kt++) {
    __syncthreads();   // buffer p staged; lut2 ready (kt==0)

    bool boundary = (kt >= 2*qt - 2) && (kt <= 2*qt + 1);
    // bias enters via the MFMA C-operand on non-boundary tiles (zero VALU)
    floatx4 cinit = boundary ? zz4 : ((kt >= 2*qt) ? bf4 : bp4);

    // ---- S'^T = K · Q'^T + bias  (Q pre-scaled by log2e) ----
    floatx4 sc[2][4];
    #pragma unroll
    for (int c = 0; c < 4; c++) {
      int rowA = (c*16 + l16)*64;
      bf16x8 ka0 = *(const bf16x8*)&Kb[p][rowA + swz0];
      bf16x8 ka1 = *(const bf16x8*)&Kb[p][rowA + swz1];
      #pragma unroll
      for (int rb = 0; rb < 2; rb++) {
        floatx4 z = __builtin_amdgcn_mfma_f32_16x16x32_bf16(ka0, qB[rb][0], cinit, 0, 0, 0);
        z = __builtin_amdgcn_mfma_f32_16x16x32_bf16(ka1, qB[rb][1], z, 0, 0, 0);
        sc[rb][c] = z;
      }
    }

    if (boundary) {
      #pragma unroll
      for (int rb = 0; rb < 2; rb++) {
        int q0 = qt*128 + rb*64 + w*16 + l16;
        #pragma unroll
        for (int c = 0; c < 4; c++) {
          int kk = kt*64 + 32*(c >> 1) + 8*quad + 4*(c & 1);
          #pragma unroll
          for (int r = 0; r < 4; r++) {
            int d = q0 - (kk + r);
            d = d < 0 ? 0 : (d > 128 ? 128 : d);
            sc[rb][c][r] += lut2[d];
          }
        }
      }
    }

    #pragma unroll
    for (int rb = 0; rb < 2; rb++)
      #pragma unroll
      for (int c = 0; c < 4; c++)
        #pragma unroll
        for (int r = 0; r < 4; r++)
          sc[rb][c][r] = exp2_fast(sc[rb][c][r]);

    // prefetch next k-tile into the other buffer
    if (kt < 31) STAGE(p^1, kt+1);

    // ---- repack P^T into B-fragments in registers (v_perm hi16 pairs) ----
    bf16x8 pf[2][2];
    #pragma unroll
    for (int rb = 0; rb < 2; rb++) {
      #pragma unroll
      for (int hh = 0; hh < 2; hh++) {
        union { bf16x8 v; unsigned u[4]; } pk;
        floatx4 a = sc[rb][2*hh], bb = sc[rb][2*hh + 1];
        pk.u[0] = __builtin_amdgcn_perm(__float_as_uint(a[1]),  __float_as_uint(a[0]),  0x07060302);
        pk.u[1] = __builtin_amdgcn_perm(__float_as_uint(a[3]),  __float_as_uint(a[2]),  0x07060302);
        pk.u[2] = __builtin_amdgcn_perm(__float_as_uint(bb[1]), __float_as_uint(bb[0]), 0x07060302);
        pk.u[3] = __builtin_amdgcn_perm(__float_as_uint(bb[3]), __float_as_uint(bb[2]), 0x07060302);
        pf[rb][hh] = pk.v;
      }
    }

    // ---- row sums via ones-A MFMA ----
    #pragma unroll
    for (int rb = 0; rb < 2; rb++) {
      li4[rb] = __builtin_amdgcn_mfma_f32_16x16x32_bf16(onesA, pf[rb][0], li4[rb], 0, 0, 0);
      li4[rb] = __builtin_amdgcn_mfma_f32_16x16x32_bf16(onesA, pf[rb][1], li4[rb], 0, 0, 0);
    }
    // ---- O^T += V^T · P^T (V reads hoisted across rb) ----
    #pragma unroll
    for (int jj = 0; jj < 4; jj++) {
      int rowV = (jj*16 + l16)*64;
      bf16x8 va0 = *(const bf16x8*)&Vb[p][rowV + swz0];
      bf16x8 va1 = *(const bf16x8*)&Vb[p][rowV + swz1];
      #pragma unroll
      for (int rb = 0; rb < 2; rb++) {
        o[rb][jj] = __builtin_amdgcn_mfma_f32_16x16x32_bf16(va0, pf[rb][0], o[rb][jj], 0, 0, 0);
        o[rb][jj] = __builtin_amdgcn_mfma_f32_16x16x32_bf16(va1, pf[rb][1], o[rb][jj], 0, 0, 0);
      }
    }
    p ^= 1;
  }

  // ---- epilogue: normalize (per-query sum is lane-local) and store ----
  #pragma unroll
  for (int rb = 0; rb < 2; rb++) {
    float inv = 1.f / li4[rb][0];
    size_t row = (size_t)(b*S_LEN + qt*128 + rb*64 + w*16 + l16);
    #pragma unroll
    for (int jj = 0; jj < 4; jj++) {
      short4 st;
      st.x = f32_bf16(o[rb][jj][0] * inv);
      st.y = f32_bf16(o[rb][jj][1] * inv);
      st.z = f32_bf16(o[rb][jj][2] * inv);
      st.w = f32_bf16(o[rb][jj][3] * inv);
      *(short4*)&ctx[row*1024 + h*64 + jj*16 + quad*4] = st;
    }
  }
  #undef STAGE
}

extern "C" void kernel_launch(void* const* d_in, const int* in_sizes, int n_in,
                              void* d_out, int out_size, void* d_ws, size_t ws_size,
                              hipStream_t stream) {
  const float* input_ids = (const float*)d_in[0];
  // d_in[1] = encoder_output (unused by the reference computation)
  const float* wq      = (const float*)d_in[2];
  const float* wk      = (const float*)d_in[3];
  const float* wv      = (const float*)d_in[4];
  const float* wo      = (const float*)d_in[5];
  const float* rel_emb = (const float*)d_in[6];
  const float* ln_w    = (const float*)d_in[7];
  float* out = (float*)d_out;

  char* ws = (char*)d_ws;
  short* xb     = (short*)ws;  ws += (size_t)8192*1024*2;   // 16 MB
  short* wqkv_t = (short*)ws;  ws += (size_t)3072*1024*2;   // 6 MB
  short* wo_t   = (short*)ws;  ws += (size_t)1024*1024*2;   // 2 MB
  short* qkv    = (short*)ws;  ws += (size_t)8192*3072*2;   // 50 MB
  short* vt     = (short*)ws;  ws += (size_t)64*64*2048*2;  // 16 MB
  short* ctx    = (short*)ws;  ws += (size_t)8192*1024*2;   // 16 MB

  rmsnorm_k<<<8192, 256, 0, stream>>>(input_ids, ln_w, xb);
  pack_wqkv_k<<<(3072*1024)/256, 256, 0, stream>>>(wq, wk, wv, wqkv_t);
  pack_wo_k<<<(1024*1024)/256, 256, 0, stream>>>(wo, wo_t);
  gemm_bt<false><<<dim3(24, 64), 256, 0, stream>>>(xb, wqkv_t, qkv, nullptr, nullptr,
                                                   8192, 3072, 1024);
  pack_vt_k<<<dim3(32, 64), 256, 0, stream>>>(qkv, vt);
  flash_k<<<dim3(16, 64), 256, 0, stream>>>(qkv, vt, rel_emb, ctx);
  gemm_bt<true><<<dim3(8, 64), 256, 0, stream>>>(ctx, wo_t, nullptr, out, input_ids,
                                                 8192, 1024, 1024);
}

// Round 6
// 321.828 us; speedup vs baseline: 1.5191x; 1.0199x over previous
//
#include <hip/hip_runtime.h>
#include <hip/hip_bf16.h>
#include <math.h>

#define S_LEN 2048
#define D_DIM 1024
#define NHEAD 16

typedef __attribute__((ext_vector_type(8))) short bf16x8;
typedef __attribute__((ext_vector_type(4))) float floatx4;

__device__ __forceinline__ short f32_bf16(float f) {
  union { float f; unsigned u; } v; v.f = f;
  unsigned r = v.u + 0x7FFFu + ((v.u >> 16) & 1u);
  return (short)(r >> 16);
}

__device__ __forceinline__ float exp2_fast(float x) {
#if __has_builtin(__builtin_amdgcn_exp2f)
  return __builtin_amdgcn_exp2f(x);
#else
  float r; asm("v_exp_f32 %0, %1" : "=v"(r) : "v"(x)); return r;
#endif
}

__device__ __forceinline__ void gload16(const void* g, void* l) {
  __builtin_amdgcn_global_load_lds((const __attribute__((address_space(1))) unsigned*)g,
                                   (__attribute__((address_space(3))) unsigned*)l,
                                   16, 0, 0);
}

// ---------------- RMSNorm (fp32 in -> bf16 out) ----------------
__global__ __launch_bounds__(256) void rmsnorm_k(const float* __restrict__ x,
                                                 const float* __restrict__ w,
                                                 short* __restrict__ out) {
  int row = blockIdx.x;
  const float4* xr = (const float4*)(x + (size_t)row * D_DIM);
  float4 v = xr[threadIdx.x];
  float ss = v.x*v.x + v.y*v.y + v.z*v.z + v.w*v.w;
  #pragma unroll
  for (int off = 32; off > 0; off >>= 1) ss += __shfl_xor(ss, off);
  __shared__ float red[4];
  if ((threadIdx.x & 63) == 0) red[threadIdx.x >> 6] = ss;
  __syncthreads();
  float scale = rsqrtf((red[0]+red[1]+red[2]+red[3]) * (1.f/D_DIM) + 1e-6f);
  float4 wv = ((const float4*)w)[threadIdx.x];
  short4 o;
  o.x = f32_bf16(v.x*scale*wv.x);
  o.y = f32_bf16(v.y*scale*wv.y);
  o.z = f32_bf16(v.z*scale*wv.z);
  o.w = f32_bf16(v.w*scale*wv.w);
  ((short4*)out)[(size_t)row*256 + threadIdx.x] = o;
}

// ---------------- weight repack: B^T layout, bf16 ----------------
// wq third is pre-scaled by log2(e) so QK^T scores come out in exp2 domain.
__global__ __launch_bounds__(256) void pack_wqkv_k(const float* __restrict__ wq,
                                                   const float* __restrict__ wk,
                                                   const float* __restrict__ wv,
                                                   short* __restrict__ o) {
  int t = blockIdx.x*256 + threadIdx.x;   // 3072*1024 elements
  int n = t >> 10, k = t & 1023;
  const float* src = (n < 1024) ? wq : ((n < 2048) ? wk : wv);
  float scale = (n < 1024) ? 1.44269504f : 1.0f;
  o[t] = f32_bf16(src[(size_t)k*1024 + (n & 1023)] * scale);
}

__global__ __launch_bounds__(256) void pack_wo_k(const float* __restrict__ wo,
                                                 short* __restrict__ o) {
  int t = blockIdx.x*256 + threadIdx.x;   // 1024*1024 elements
  int n = t >> 10, k = t & 1023;
  o[t] = f32_bf16(wo[(size_t)k*1024 + n]);
}

// ---------------- GEMM: C[M,N] = A[M,K] * Bt[N,K]^T (+residual) ----------------
// BK=64, XOR-chunk-swizzled LDS (rows of 64 elems, phys chunk = logical ^ (row&7)).
// Two MFMA sub-bodies per barrier pair: half the barriers of the BK=32 version.
template<bool ADD_RES>
__global__ __launch_bounds__(256) void gemm_bt(const short* __restrict__ A,
                                               const short* __restrict__ Bt,
                                               short* __restrict__ Cb,
                                               float* __restrict__ Cf,
                                               const float* __restrict__ res,
                                               int M, int N, int K) {
  constexpr int BK = 64;
  __shared__ __align__(16) short As[128*BK];
  __shared__ __align__(16) short Bs[128*BK];
  int tid = threadIdx.x;
  int w = tid >> 6, lane = tid & 63, quad = lane >> 4, l16 = lane & 15;
  int wr = w >> 1, wc = w & 1;
  int bn = blockIdx.x, bm = blockIdx.y;
  const short* Ag = A + (size_t)bm * 128 * K;
  const short* Bg = Bt + (size_t)bn * 128 * K;
  const int srow = lane >> 3;            // 0..7
  const int slc  = (lane & 7) ^ srow;    // logical chunk fetched into phys chunk lane&7

  floatx4 acc[4][4] = {};

  for (int k0 = 0; k0 < K; k0 += BK) {
    #pragma unroll
    for (int i = 0; i < 4; i++) {
      int rbase = w*32 + i*8;
      gload16(Ag + (size_t)(rbase + srow) * K + k0 + slc*8, &As[rbase*BK]);
      gload16(Bg + (size_t)(rbase + srow) * K + k0 + slc*8, &Bs[rbase*BK]);
    }
    __syncthreads();
    #pragma unroll
    for (int h = 0; h < 2; h++) {
      int sw = ((quad + 4*h) ^ (l16 & 7)) * 8;
      bf16x8 af[4], bfr[4];
      #pragma unroll
      for (int i = 0; i < 4; i++) {
        af[i]  = *(const bf16x8*)&As[(wr*64 + i*16 + l16)*BK + sw];
        bfr[i] = *(const bf16x8*)&Bs[(wc*64 + i*16 + l16)*BK + sw];
      }
      #pragma unroll
      for (int i = 0; i < 4; i++)
        #pragma unroll
        for (int j = 0; j < 4; j++)
          acc[i][j] = __builtin_amdgcn_mfma_f32_16x16x32_bf16(af[i], bfr[j], acc[i][j], 0, 0, 0);
    }
    __syncthreads();
  }

  #pragma unroll
  for (int i = 0; i < 4; i++) {
    int row0 = bm*128 + wr*64 + i*16 + quad*4;
    #pragma unroll
    for (int j = 0; j < 4; j++) {
      int col = bn*128 + wc*64 + j*16 + l16;
      #pragma unroll
      for (int r = 0; r < 4; r++) {
        size_t idx = (size_t)(row0 + r) * N + col;
        if (ADD_RES) Cf[idx] = res[idx] + acc[i][j][r];
        else         Cb[idx] = f32_bf16(acc[i][j][r]);
      }
    }
  }
}

// ---------------- V transpose pack: vt[bh][hd][s] ----------------
__global__ __launch_bounds__(256) void pack_vt_k(const short* __restrict__ qkv,
                                                 short* __restrict__ vt) {
  __shared__ __align__(16) short tile[64][72];
  int s0 = blockIdx.x * 64;
  int bh = blockIdx.y;
  int b = bh >> 4, h = bh & 15;
  int t = threadIdx.x;
  #pragma unroll
  for (int i = 0; i < 2; i++) {
    int idx = t + i*256;
    int s = idx >> 3, c = idx & 7;
    *(bf16x8*)&tile[s][c*8] =
      *(const bf16x8*)&qkv[(size_t)(b*S_LEN + s0 + s)*3072 + 2048 + h*64 + c*8];
  }
  __syncthreads();
  #pragma unroll
  for (int i = 0; i < 2; i++) {
    int idx = t + i*256;
    int hd = idx >> 3, c = idx & 7;
    short tmp[8];
    #pragma unroll
    for (int j = 0; j < 8; j++) tmp[j] = tile[c*8 + j][hd];
    *(bf16x8*)&vt[((size_t)(bh*64 + hd))*S_LEN + s0 + c*8] = *(bf16x8*)tmp;
  }
}

// ---------------- Flash attention v5: transposed-score structure, bias via
// MFMA C-operand, raw v_exp_f32, Q pre-scaled by log2e, kt-loop unrolled x2
// (literal buffer index), loop-invariant staging addresses.
__global__ __launch_bounds__(256) void flash_k(const short* __restrict__ qkv,
                                               const short* __restrict__ vt,
                                               const float* __restrict__ rel_emb,
                                               short* __restrict__ ctx) {
  __shared__ __align__(16) short Kb[2][64*64];   // rows = permuted keys, cols = d
  __shared__ __align__(16) short Vb[2][64*64];   // rows = hd, cols = keys (natural)
  __shared__ float lut2[132];                    // bias * log2(e)

  const int qt = blockIdx.x, bh = blockIdx.y;
  const int b = bh >> 4, h = bh & 15;
  const int t = threadIdx.x, w = t >> 6, lane = t & 63, quad = lane >> 4, l16 = lane & 15;
  const float L2E = 1.44269504f;

  if (t < 129) {
    int rp = t, bucket;
    if (rp < 16) bucket = rp;
    else {
      bucket = 16 + (int)(logf((float)rp * 0.0625f) * (16.f / logf(8.f)));
      if (bucket > 31) bucket = 31;
    }
    lut2[t] = rel_emb[bucket*16 + h] * L2E;
  }
  const float bfut  = rel_emb[h] * L2E;            // d <= 0  -> bucket 0
  const float bpast = rel_emb[31*16 + h] * L2E;    // d >= 128 -> bucket 31
  const floatx4 bf4 = {bfut, bfut, bfut, bfut};
  const floatx4 bp4 = {bpast, bpast, bpast, bpast};
  const floatx4 zz4 = {0.f, 0.f, 0.f, 0.f};

  const int srow = lane >> 3;
  const int slc  = (lane & 7) ^ srow;
  // permuted key for K-tile LDS row w*16+srow
  const int kperm = 32*(w >> 1) + 8*(srow >> 2) + 4*(w & 1) + (srow & 3);

  // loop-invariant staging bases: uniform pointer + fixed lane offset
  const short* kgU = qkv + ((size_t)b*S_LEN)*3072 + 1024 + h*64;  // wave-uniform
  const int    loK = kperm*3072 + slc*8;                           // lane-const
  const short* vgU = vt + ((size_t)bh*64)*2048;
  const int    loV = (w*16 + srow)*2048 + slc*8;

  // Q fragments: lane l16 = query (B-operand n-dim), elems = d (quad*8+j)
  bf16x8 qB[2][2];
  #pragma unroll
  for (int rb = 0; rb < 2; rb++) {
    const short* qb = qkv + ((size_t)(b*S_LEN + qt*128 + rb*64 + w*16 + l16))*3072 + h*64;
    qB[rb][0] = *(const bf16x8*)&qb[quad*8];
    qB[rb][1] = *(const bf16x8*)&qb[32 + quad*8];
  }

  floatx4 o[2][4] = {};      // O^T accumulators: row=d(quad*4+r), col=query(l16)
  floatx4 li4[2] = {};       // row sums per query
  const short ONE = (short)0x3F80;
  bf16x8 onesA = {ONE, ONE, ONE, ONE, ONE, ONE, ONE, ONE};

  const int swz0 = (quad     ^ (l16 & 7)) * 8;
  const int swz1 = ((quad+4) ^ (l16 & 7)) * 8;

  #define STAGE(P_, KT_) do {                                                   \
    const short* ka_ = kgU + (size_t)(KT_)*196608 + loK;                        \
    gload16(ka_,          &Kb[P_][(w*16    )*64]);                              \
    gload16(ka_ + 49152,  &Kb[P_][(w*16 + 8)*64]);                              \
    const short* va_ = vgU + loV + (KT_)*64;                                    \
    gload16(va_,          &Vb[P_][(w*16    )*64]);                              \
    gload16(va_ + 16384,  &Vb[P_][(w*16 + 8)*64]);                              \
  } while (0)

  #define BODY(P_, KT_) do {                                                    \
    __syncthreads();                                                            \
    bool boundary = ((KT_) >= 2*qt - 2) && ((KT_) <= 2*qt + 1);                 \
    floatx4 cinit = boundary ? zz4 : (((KT_) >= 2*qt) ? bf4 : bp4);             \
    floatx4 sc[2][4];                                                           \
    _Pragma("unroll")                                                           \
    for (int c = 0; c < 4; c++) {                                               \
      int rowA = (c*16 + l16)*64;                                               \
      bf16x8 ka0 = *(const bf16x8*)&Kb[P_][rowA + swz0];                        \
      bf16x8 ka1 = *(const bf16x8*)&Kb[P_][rowA + swz1];                        \
      _Pragma("unroll")                                                         \
      for (int rb = 0; rb < 2; rb++) {                                          \
        floatx4 z = __builtin_amdgcn_mfma_f32_16x16x32_bf16(ka0, qB[rb][0], cinit, 0, 0, 0); \
        z = __builtin_amdgcn_mfma_f32_16x16x32_bf16(ka1, qB[rb][1], z, 0, 0, 0);\
        sc[rb][c] = z;                                                          \
      }                                                                         \
    }                                                                           \
    if (boundary) {                                                             \
      _Pragma("unroll")                                                         \
      for (int rb = 0; rb < 2; rb++) {                                          \
        int q0 = qt*128 + rb*64 + w*16 + l16;                                   \
        _Pragma("unroll")                                                       \
        for (int c = 0; c < 4; c++) {                                           \
          int kk = (KT_)*64 + 32*(c >> 1) + 8*quad + 4*(c & 1);                 \
          _Pragma("unroll")                                                     \
          for (int r = 0; r < 4; r++) {                                         \
            int d = q0 - (kk + r);                                              \
            d = d < 0 ? 0 : (d > 128 ? 128 : d);                                \
            sc[rb][c][r] += lut2[d];                                            \
          }                                                                     \
        }                                                                       \
      }                                                                         \
    }                                                                           \
    _Pragma("unroll")                                                           \
    for (int rb = 0; rb < 2; rb++)                                              \
      _Pragma("unroll")                                                         \
      for (int c = 0; c < 4; c++)                                               \
        _Pragma("unroll")                                                       \
        for (int r = 0; r < 4; r++)                                             \
          sc[rb][c][r] = exp2_fast(sc[rb][c][r]);                               \
    if ((KT_) < 31) STAGE((P_) ^ 1, (KT_) + 1);                                 \
    bf16x8 pf[2][2];                                                            \
    _Pragma("unroll")                                                           \
    for (int rb = 0; rb < 2; rb++) {                                            \
      _Pragma("unroll")                                                         \
      for (int hh = 0; hh < 2; hh++) {                                          \
        union { bf16x8 v; unsigned u[4]; } pk;                                  \
        floatx4 a = sc[rb][2*hh], bb = sc[rb][2*hh + 1];                        \
        pk.u[0] = __builtin_amdgcn_perm(__float_as_uint(a[1]),  __float_as_uint(a[0]),  0x07060302); \
        pk.u[1] = __builtin_amdgcn_perm(__float_as_uint(a[3]),  __float_as_uint(a[2]),  0x07060302); \
        pk.u[2] = __builtin_amdgcn_perm(__float_as_uint(bb[1]), __float_as_uint(bb[0]), 0x07060302); \
        pk.u[3] = __builtin_amdgcn_perm(__float_as_uint(bb[3]), __float_as_uint(bb[2]), 0x07060302); \
        pf[rb][hh] = pk.v;                                                      \
      }                                                                         \
    }                                                                           \
    _Pragma("unroll")                                                           \
    for (int rb = 0; rb < 2; rb++) {                                            \
      li4[rb] = __builtin_amdgcn_mfma_f32_16x16x32_bf16(onesA, pf[rb][0], li4[rb], 0, 0, 0); \
      li4[rb] = __builtin_amdgcn_mfma_f32_16x16x32_bf16(onesA, pf[rb][1], li4[rb], 0, 0, 0); \
    }                                                                           \
    _Pragma("unroll")                                                           \
    for (int jj = 0; jj < 4; jj++) {                                            \
      int rowV = (jj*16 + l16)*64;                                              \
      bf16x8 va0 = *(const bf16x8*)&Vb[P_][rowV + swz0];                        \
      bf16x8 va1 = *(const bf16x8*)&Vb[P_][rowV + swz1];                        \
      _Pragma("unroll")                                                         \
      for (int rb = 0; rb < 2; rb++) {                                          \
        o[rb][jj] = __builtin_amdgcn_mfma_f32_16x16x32_bf16(va0, pf[rb][0], o[rb][jj], 0, 0, 0); \
        o[rb][jj] = __builtin_amdgcn_mfma_f32_16x16x32_bf16(va1, pf[rb][1], o[rb][jj], 0, 0, 0); \
      }                                                                         \
    }                                                                           \
  } while (0)

  STAGE(0, 0);
  for (int kt = 0; kt < 32; kt += 2) {
    BODY(0, kt);
    BODY(1, kt + 1);
  }

  // ---- epilogue: normalize (per-query sum is lane-local) and store ----
  #pragma unroll
  for (int rb = 0; rb < 2; rb++) {
    float inv = 1.f / li4[rb][0];
    size_t row = (size_t)(b*S_LEN + qt*128 + rb*64 + w*16 + l16);
    #pragma unroll
    for (int jj = 0; jj < 4; jj++) {
      short4 st;
      st.x = f32_bf16(o[rb][jj][0] * inv);
      st.y = f32_bf16(o[rb][jj][1] * inv);
      st.z = f32_bf16(o[rb][jj][2] * inv);
      st.w = f32_bf16(o[rb][jj][3] * inv);
      *(short4*)&ctx[row*1024 + h*64 + jj*16 + quad*4] = st;
    }
  }
  #undef STAGE
  #undef BODY
}

extern "C" void kernel_launch(void* const* d_in, const int* in_sizes, int n_in,
                              void* d_out, int out_size, void* d_ws, size_t ws_size,
                              hipStream_t stream) {
  const float* input_ids = (const float*)d_in[0];
  // d_in[1] = encoder_output (unused by the reference computation)
  const float* wq      = (const float*)d_in[2];
  const float* wk      = (const float*)d_in[3];
  const float* wv      = (const float*)d_in[4];
  const float* wo      = (const float*)d_in[5];
  const float* rel_emb = (const float*)d_in[6];
  const float* ln_w    = (const float*)d_in[7];
  float* out = (float*)d_out;

  char* ws = (char*)d_ws;
  short* xb     = (short*)ws;  ws += (size_t)8192*1024*2;   // 16 MB
  short* wqkv_t = (short*)ws;  ws += (size_t)3072*1024*2;   // 6 MB
  short* wo_t   = (short*)ws;  ws += (size_t)1024*1024*2;   // 2 MB
  short* qkv    = (short*)ws;  ws += (size_t)8192*3072*2;   // 50 MB
  short* vt     = (short*)ws;  ws += (size_t)64*64*2048*2;  // 16 MB
  short* ctx    = (short*)ws;  ws += (size_t)8192*1024*2;   // 16 MB

  rmsnorm_k<<<8192, 256, 0, stream>>>(input_ids, ln_w, xb);
  pack_wqkv_k<<<(3072*1024)/256, 256, 0, stream>>>(wq, wk, wv, wqkv_t);
  pack_wo_k<<<(1024*1024)/256, 256, 0, stream>>>(wo, wo_t);
  gemm_bt<false><<<dim3(24, 64), 256, 0, stream>>>(xb, wqkv_t, qkv, nullptr, nullptr,
                                                   8192, 3072, 1024);
  pack_vt_k<<<dim3(32, 64), 256, 0, stream>>>(qkv, vt);
  flash_k<<<dim3(16, 64), 256, 0, stream>>>(qkv, vt, rel_emb, ctx);
  gemm_bt<true><<<dim3(8, 64), 256, 0, stream>>>(ctx, wo_t, nullptr, out, input_ids,
                                                 8192, 1024, 1024);
}

// Round 7
// 298.085 us; speedup vs baseline: 1.6401x; 1.0797x over previous
//
#include <hip/hip_runtime.h>
#include <hip/hip_bf16.h>
#include <math.h>

#define S_LEN 2048
#define D_DIM 1024
#define NHEAD 16

typedef __attribute__((ext_vector_type(8))) short bf16x8;
typedef __attribute__((ext_vector_type(4))) float floatx4;

__device__ __forceinline__ short f32_bf16(float f) {
  union { float f; unsigned u; } v; v.f = f;
  unsigned r = v.u + 0x7FFFu + ((v.u >> 16) & 1u);
  return (short)(r >> 16);
}

__device__ __forceinline__ float exp2_fast(float x) {
#if __has_builtin(__builtin_amdgcn_exp2f)
  return __builtin_amdgcn_exp2f(x);
#else
  float r; asm("v_exp_f32 %0, %1" : "=v"(r) : "v"(x)); return r;
#endif
}

__device__ __forceinline__ void gload16(const void* g, void* l) {
  __builtin_amdgcn_global_load_lds((const __attribute__((address_space(1))) unsigned*)g,
                                   (__attribute__((address_space(3))) unsigned*)l,
                                   16, 0, 0);
}

// ---------------- RMSNorm (fp32 in -> bf16 out) ----------------
__global__ __launch_bounds__(256) void rmsnorm_k(const float* __restrict__ x,
                                                 const float* __restrict__ w,
                                                 short* __restrict__ out) {
  int row = blockIdx.x;
  const float4* xr = (const float4*)(x + (size_t)row * D_DIM);
  float4 v = xr[threadIdx.x];
  float ss = v.x*v.x + v.y*v.y + v.z*v.z + v.w*v.w;
  #pragma unroll
  for (int off = 32; off > 0; off >>= 1) ss += __shfl_xor(ss, off);
  __shared__ float red[4];
  if ((threadIdx.x & 63) == 0) red[threadIdx.x >> 6] = ss;
  __syncthreads();
  float scale = rsqrtf((red[0]+red[1]+red[2]+red[3]) * (1.f/D_DIM) + 1e-6f);
  float4 wv = ((const float4*)w)[threadIdx.x];
  short4 o;
  o.x = f32_bf16(v.x*scale*wv.x);
  o.y = f32_bf16(v.y*scale*wv.y);
  o.z = f32_bf16(v.z*scale*wv.z);
  o.w = f32_bf16(v.w*scale*wv.w);
  ((short4*)out)[(size_t)row*256 + threadIdx.x] = o;
}

// ---------------- weight repack: B^T layout, bf16 ----------------
// wq third is pre-scaled by log2(e) so QK^T scores come out in exp2 domain.
__global__ __launch_bounds__(256) void pack_wqkv_k(const float* __restrict__ wq,
                                                   const float* __restrict__ wk,
                                                   const float* __restrict__ wv,
                                                   short* __restrict__ o) {
  int t = blockIdx.x*256 + threadIdx.x;   // 3072*1024 elements
  int n = t >> 10, k = t & 1023;
  const float* src = (n < 1024) ? wq : ((n < 2048) ? wk : wv);
  float scale = (n < 1024) ? 1.44269504f : 1.0f;
  o[t] = f32_bf16(src[(size_t)k*1024 + (n & 1023)] * scale);
}

__global__ __launch_bounds__(256) void pack_wo_k(const float* __restrict__ wo,
                                                 short* __restrict__ o) {
  int t = blockIdx.x*256 + threadIdx.x;   // 1024*1024 elements
  int n = t >> 10, k = t & 1023;
  o[t] = f32_bf16(wo[(size_t)k*1024 + n]);
}

// ---------------- GEMM: C[M,N] = A[M,K] * Bt[N,K]^T (+residual) ----------------
// BK=64, XOR-chunk-swizzled LDS (rows of 64 elems, phys chunk = logical ^ (row&7)).
template<bool ADD_RES>
__global__ __launch_bounds__(256) void gemm_bt(const short* __restrict__ A,
                                               const short* __restrict__ Bt,
                                               short* __restrict__ Cb,
                                               float* __restrict__ Cf,
                                               const float* __restrict__ res,
                                               int M, int N, int K) {
  constexpr int BK = 64;
  __shared__ __align__(16) short As[128*BK];
  __shared__ __align__(16) short Bs[128*BK];
  int tid = threadIdx.x;
  int w = tid >> 6, lane = tid & 63, quad = lane >> 4, l16 = lane & 15;
  int wr = w >> 1, wc = w & 1;
  int bn = blockIdx.x, bm = blockIdx.y;
  const short* Ag = A + (size_t)bm * 128 * K;
  const short* Bg = Bt + (size_t)bn * 128 * K;
  const int srow = lane >> 3;            // 0..7
  const int slc  = (lane & 7) ^ srow;    // logical chunk fetched into phys chunk lane&7

  floatx4 acc[4][4] = {};

  for (int k0 = 0; k0 < K; k0 += BK) {
    #pragma unroll
    for (int i = 0; i < 4; i++) {
      int rbase = w*32 + i*8;
      gload16(Ag + (size_t)(rbase + srow) * K + k0 + slc*8, &As[rbase*BK]);
      gload16(Bg + (size_t)(rbase + srow) * K + k0 + slc*8, &Bs[rbase*BK]);
    }
    __syncthreads();
    #pragma unroll
    for (int h = 0; h < 2; h++) {
      int sw = ((quad + 4*h) ^ (l16 & 7)) * 8;
      bf16x8 af[4], bfr[4];
      #pragma unroll
      for (int i = 0; i < 4; i++) {
        af[i]  = *(const bf16x8*)&As[(wr*64 + i*16 + l16)*BK + sw];
        bfr[i] = *(const bf16x8*)&Bs[(wc*64 + i*16 + l16)*BK + sw];
      }
      #pragma unroll
      for (int i = 0; i < 4; i++)
        #pragma unroll
        for (int j = 0; j < 4; j++)
          acc[i][j] = __builtin_amdgcn_mfma_f32_16x16x32_bf16(af[i], bfr[j], acc[i][j], 0, 0, 0);
    }
    __syncthreads();
  }

  #pragma unroll
  for (int i = 0; i < 4; i++) {
    int row0 = bm*128 + wr*64 + i*16 + quad*4;
    #pragma unroll
    for (int j = 0; j < 4; j++) {
      int col = bn*128 + wc*64 + j*16 + l16;
      #pragma unroll
      for (int r = 0; r < 4; r++) {
        size_t idx = (size_t)(row0 + r) * N + col;
        if (ADD_RES) Cf[idx] = res[idx] + acc[i][j][r];
        else         Cb[idx] = f32_bf16(acc[i][j][r]);
      }
    }
  }
}

// ---------------- V transpose pack: vt[bh][hd][s] ----------------
__global__ __launch_bounds__(256) void pack_vt_k(const short* __restrict__ qkv,
                                                 short* __restrict__ vt) {
  __shared__ __align__(16) short tile[64][72];
  int s0 = blockIdx.x * 64;
  int bh = blockIdx.y;
  int b = bh >> 4, h = bh & 15;
  int t = threadIdx.x;
  #pragma unroll
  for (int i = 0; i < 2; i++) {
    int idx = t + i*256;
    int s = idx >> 3, c = idx & 7;
    *(bf16x8*)&tile[s][c*8] =
      *(const bf16x8*)&qkv[(size_t)(b*S_LEN + s0 + s)*3072 + 2048 + h*64 + c*8];
  }
  __syncthreads();
  #pragma unroll
  for (int i = 0; i < 2; i++) {
    int idx = t + i*256;
    int hd = idx >> 3, c = idx & 7;
    short tmp[8];
    #pragma unroll
    for (int j = 0; j < 8; j++) tmp[j] = tile[c*8 + j][hd];
    *(bf16x8*)&vt[((size_t)(bh*64 + hd))*S_LEN + s0 + c*8] = *(bf16x8*)tmp;
  }
}

// ---------------- Flash attention v6: 256 queries/block (512 threads),
// XCD-swizzled bh grouping (per-XCD K/V working set = 4 MB = one L2),
// prefetch issued at top of body, transposed-score register softmax.
__global__ __launch_bounds__(512) void flash_k(const short* __restrict__ qkv,
                                               const short* __restrict__ vt,
                                               const float* __restrict__ rel_emb,
                                               short* __restrict__ ctx) {
  __shared__ __align__(16) short Kb[2][64*64];   // rows = permuted keys, cols = d
  __shared__ __align__(16) short Vb[2][64*64];   // rows = hd, cols = keys (natural)
  __shared__ float lut2[132];                    // bias * log2(e)

  // XCD-aware swizzle: linear id L; xcd = L&7 (round-robin dispatch heuristic);
  // each xcd owns bh in [xcd*8, xcd*8+8) -> K/V working set 4 MB = one L2.
  const int L = blockIdx.x + 8*blockIdx.y;   // grid (8,64) = 512 blocks
  const int xcd = L & 7, kk_ = L >> 3;
  const int bh = xcd*8 + (kk_ >> 3);
  const int qt = kk_ & 7;
  const int b = bh >> 4, h = bh & 15;
  const int t = threadIdx.x, w = t >> 6, lane = t & 63, quad = lane >> 4, l16 = lane & 15;
  const float L2E = 1.44269504f;

  if (t < 129) {
    int rp = t, bucket;
    if (rp < 16) bucket = rp;
    else {
      bucket = 16 + (int)(logf((float)rp * 0.0625f) * (16.f / logf(8.f)));
      if (bucket > 31) bucket = 31;
    }
    lut2[t] = rel_emb[bucket*16 + h] * L2E;
  }
  const float bfut  = rel_emb[h] * L2E;            // d <= 0  -> bucket 0
  const float bpast = rel_emb[31*16 + h] * L2E;    // d >= 128 -> bucket 31
  const floatx4 bf4 = {bfut, bfut, bfut, bfut};
  const floatx4 bp4 = {bpast, bpast, bpast, bpast};
  const floatx4 zz4 = {0.f, 0.f, 0.f, 0.f};

  const int srow = lane >> 3;          // 0..7
  const int slc  = (lane & 7) ^ srow;  // XOR chunk swizzle
  // wave w stages K rows [w*8, w*8+8); LDS row rho holds key perm(rho)
  const int rho  = w*8 + srow;
  const int kperm = 32*(rho >> 5) + 8*((rho >> 2) & 3) + 4*((rho >> 4) & 1) + (rho & 3);

  // loop-invariant staging bases
  const short* kgU = qkv + ((size_t)b*S_LEN)*3072 + 1024 + h*64;  // wave-uniform
  const int    loK = kperm*3072 + slc*8;                           // lane-const
  const short* vgU = vt + ((size_t)bh*64)*2048;
  const int    loV = rho*2048 + slc*8;

  // Q fragments: lane l16 = query (B-operand n-dim), elems = d (quad*8+j)
  bf16x8 qB[2][2];
  #pragma unroll
  for (int rb = 0; rb < 2; rb++) {
    const short* qb = qkv + ((size_t)(b*S_LEN + qt*256 + rb*128 + w*16 + l16))*3072 + h*64;
    qB[rb][0] = *(const bf16x8*)&qb[quad*8];
    qB[rb][1] = *(const bf16x8*)&qb[32 + quad*8];
  }

  floatx4 o[2][4] = {};      // O^T accumulators: row=d(quad*4+r), col=query(l16)
  floatx4 li4[2] = {};       // row sums per query
  const short ONE = (short)0x3F80;
  bf16x8 onesA = {ONE, ONE, ONE, ONE, ONE, ONE, ONE, ONE};

  const int swz0 = (quad     ^ (l16 & 7)) * 8;
  const int swz1 = ((quad+4) ^ (l16 & 7)) * 8;

  #define STAGE(P_, KT_) do {                                                   \
    const short* ka_ = kgU + (size_t)(KT_)*196608 + loK;                        \
    gload16(ka_, &Kb[P_][(w*8)*64]);                                            \
    const short* va_ = vgU + loV + (KT_)*64;                                    \
    gload16(va_, &Vb[P_][(w*8)*64]);                                            \
  } while (0)

  #define BODY(P_, KT_) do {                                                    \
    __syncthreads();                                                            \
    if ((KT_) < 31) STAGE((P_) ^ 1, (KT_) + 1);   /* max prefetch distance */   \
    bool boundary = ((KT_) >= 4*qt - 2) && ((KT_) <= 4*qt + 3);                 \
    floatx4 cinit = boundary ? zz4 : (((KT_) >= 4*qt) ? bf4 : bp4);             \
    floatx4 sc[2][4];                                                           \
    _Pragma("unroll")                                                           \
    for (int c = 0; c < 4; c++) {                                               \
      int rowA = (c*16 + l16)*64;                                               \
      bf16x8 ka0 = *(const bf16x8*)&Kb[P_][rowA + swz0];                        \
      bf16x8 ka1 = *(const bf16x8*)&Kb[P_][rowA + swz1];                        \
      _Pragma("unroll")                                                         \
      for (int rb = 0; rb < 2; rb++) {                                          \
        floatx4 z = __builtin_amdgcn_mfma_f32_16x16x32_bf16(ka0, qB[rb][0], cinit, 0, 0, 0); \
        z = __builtin_amdgcn_mfma_f32_16x16x32_bf16(ka1, qB[rb][1], z, 0, 0, 0);\
        sc[rb][c] = z;                                                          \
      }                                                                         \
    }                                                                           \
    if (boundary) {                                                             \
      _Pragma("unroll")                                                         \
      for (int rb = 0; rb < 2; rb++) {                                          \
        int q0 = qt*256 + rb*128 + w*16 + l16;                                  \
        _Pragma("unroll")                                                       \
        for (int c = 0; c < 4; c++) {                                           \
          int kk = (KT_)*64 + 32*(c >> 1) + 8*quad + 4*(c & 1);                 \
          _Pragma("unroll")                                                     \
          for (int r = 0; r < 4; r++) {                                         \
            int d = q0 - (kk + r);                                              \
            d = d < 0 ? 0 : (d > 128 ? 128 : d);                                \
            sc[rb][c][r] += lut2[d];                                            \
          }                                                                     \
        }                                                                       \
      }                                                                         \
    }                                                                           \
    _Pragma("unroll")                                                           \
    for (int rb = 0; rb < 2; rb++)                                              \
      _Pragma("unroll")                                                         \
      for (int c = 0; c < 4; c++)                                               \
        _Pragma("unroll")                                                       \
        for (int r = 0; r < 4; r++)                                             \
          sc[rb][c][r] = exp2_fast(sc[rb][c][r]);                               \
    bf16x8 pf[2][2];                                                            \
    _Pragma("unroll")                                                           \
    for (int rb = 0; rb < 2; rb++) {                                            \
      _Pragma("unroll")                                                         \
      for (int hh = 0; hh < 2; hh++) {                                          \
        union { bf16x8 v; unsigned u[4]; } pk;                                  \
        floatx4 a = sc[rb][2*hh], bb = sc[rb][2*hh + 1];                        \
        pk.u[0] = __builtin_amdgcn_perm(__float_as_uint(a[1]),  __float_as_uint(a[0]),  0x07060302); \
        pk.u[1] = __builtin_amdgcn_perm(__float_as_uint(a[3]),  __float_as_uint(a[2]),  0x07060302); \
        pk.u[2] = __builtin_amdgcn_perm(__float_as_uint(bb[1]), __float_as_uint(bb[0]), 0x07060302); \
        pk.u[3] = __builtin_amdgcn_perm(__float_as_uint(bb[3]), __float_as_uint(bb[2]), 0x07060302); \
        pf[rb][hh] = pk.v;                                                      \
      }                                                                         \
    }                                                                           \
    _Pragma("unroll")                                                           \
    for (int rb = 0; rb < 2; rb++) {                                            \
      li4[rb] = __builtin_amdgcn_mfma_f32_16x16x32_bf16(onesA, pf[rb][0], li4[rb], 0, 0, 0); \
      li4[rb] = __builtin_amdgcn_mfma_f32_16x16x32_bf16(onesA, pf[rb][1], li4[rb], 0, 0, 0); \
    }                                                                           \
    _Pragma("unroll")                                                           \
    for (int jj = 0; jj < 4; jj++) {                                            \
      int rowV = (jj*16 + l16)*64;                                              \
      bf16x8 va0 = *(const bf16x8*)&Vb[P_][rowV + swz0];                        \
      bf16x8 va1 = *(const bf16x8*)&Vb[P_][rowV + swz1];                        \
      _Pragma("unroll")                                                         \
      for (int rb = 0; rb < 2; rb++) {                                          \
        o[rb][jj] = __builtin_amdgcn_mfma_f32_16x16x32_bf16(va0, pf[rb][0], o[rb][jj], 0, 0, 0); \
        o[rb][jj] = __builtin_amdgcn_mfma_f32_16x16x32_bf16(va1, pf[rb][1], o[rb][jj], 0, 0, 0); \
      }                                                                         \
    }                                                                           \
  } while (0)

  STAGE(0, 0);
  for (int kt = 0; kt < 32; kt += 2) {
    BODY(0, kt);
    BODY(1, kt + 1);
  }

  // ---- epilogue: normalize (per-query sum is lane-local) and store ----
  #pragma unroll
  for (int rb = 0; rb < 2; rb++) {
    float inv = 1.f / li4[rb][0];
    size_t row = (size_t)(b*S_LEN + qt*256 + rb*128 + w*16 + l16);
    #pragma unroll
    for (int jj = 0; jj < 4; jj++) {
      short4 st;
      st.x = f32_bf16(o[rb][jj][0] * inv);
      st.y = f32_bf16(o[rb][jj][1] * inv);
      st.z = f32_bf16(o[rb][jj][2] * inv);
      st.w = f32_bf16(o[rb][jj][3] * inv);
      *(short4*)&ctx[row*1024 + h*64 + jj*16 + quad*4] = st;
    }
  }
  #undef STAGE
  #undef BODY
}

extern "C" void kernel_launch(void* const* d_in, const int* in_sizes, int n_in,
                              void* d_out, int out_size, void* d_ws, size_t ws_size,
                              hipStream_t stream) {
  const float* input_ids = (const float*)d_in[0];
  // d_in[1] = encoder_output (unused by the reference computation)
  const float* wq      = (const float*)d_in[2];
  const float* wk      = (const float*)d_in[3];
  const float* wv      = (const float*)d_in[4];
  const float* wo      = (const float*)d_in[5];
  const float* rel_emb = (const float*)d_in[6];
  const float* ln_w    = (const float*)d_in[7];
  float* out = (float*)d_out;

  char* ws = (char*)d_ws;
  short* xb     = (short*)ws;  ws += (size_t)8192*1024*2;   // 16 MB
  short* wqkv_t = (short*)ws;  ws += (size_t)3072*1024*2;   // 6 MB
  short* wo_t   = (short*)ws;  ws += (size_t)1024*1024*2;   // 2 MB
  short* qkv    = (short*)ws;  ws += (size_t)8192*3072*2;   // 50 MB
  short* vt     = (short*)ws;  ws += (size_t)64*64*2048*2;  // 16 MB
  short* ctx    = (short*)ws;  ws += (size_t)8192*1024*2;   // 16 MB

  rmsnorm_k<<<8192, 256, 0, stream>>>(input_ids, ln_w, xb);
  pack_wqkv_k<<<(3072*1024)/256, 256, 0, stream>>>(wq, wk, wv, wqkv_t);
  pack_wo_k<<<(1024*1024)/256, 256, 0, stream>>>(wo, wo_t);
  gemm_bt<false><<<dim3(24, 64), 256, 0, stream>>>(xb, wqkv_t, qkv, nullptr, nullptr,
                                                   8192, 3072, 1024);
  pack_vt_k<<<dim3(32, 64), 256, 0, stream>>>(qkv, vt);
  flash_k<<<dim3(8, 64), 512, 0, stream>>>(qkv, vt, rel_emb, ctx);
  gemm_bt<true><<<dim3(8, 64), 256, 0, stream>>>(ctx, wo_t, nullptr, out, input_ids,
                                                 8192, 1024, 1024);
}

// Round 8
// 292.302 us; speedup vs baseline: 1.6725x; 1.0198x over previous
//
#include <hip/hip_runtime.h>
#include <hip/hip_bf16.h>
#include <math.h>

#define S_LEN 2048
#define D_DIM 1024
#define NHEAD 16

typedef __attribute__((ext_vector_type(8))) short bf16x8;
typedef __attribute__((ext_vector_type(4))) float floatx4;

__device__ __forceinline__ short f32_bf16(float f) {
  union { float f; unsigned u; } v; v.f = f;
  unsigned r = v.u + 0x7FFFu + ((v.u >> 16) & 1u);
  return (short)(r >> 16);
}

__device__ __forceinline__ float exp2_fast(float x) {
#if __has_builtin(__builtin_amdgcn_exp2f)
  return __builtin_amdgcn_exp2f(x);
#else
  float r; asm("v_exp_f32 %0, %1" : "=v"(r) : "v"(x)); return r;
#endif
}

__device__ __forceinline__ void gload16(const void* g, void* l) {
  __builtin_amdgcn_global_load_lds((const __attribute__((address_space(1))) unsigned*)g,
                                   (__attribute__((address_space(3))) unsigned*)l,
                                   16, 0, 0);
}

// ---------------- RMSNorm (fp32 in -> bf16 out) ----------------
__global__ __launch_bounds__(256) void rmsnorm_k(const float* __restrict__ x,
                                                 const float* __restrict__ w,
                                                 short* __restrict__ out) {
  int row = blockIdx.x;
  const float4* xr = (const float4*)(x + (size_t)row * D_DIM);
  float4 v = xr[threadIdx.x];
  float ss = v.x*v.x + v.y*v.y + v.z*v.z + v.w*v.w;
  #pragma unroll
  for (int off = 32; off > 0; off >>= 1) ss += __shfl_xor(ss, off);
  __shared__ float red[4];
  if ((threadIdx.x & 63) == 0) red[threadIdx.x >> 6] = ss;
  __syncthreads();
  float scale = rsqrtf((red[0]+red[1]+red[2]+red[3]) * (1.f/D_DIM) + 1e-6f);
  float4 wv = ((const float4*)w)[threadIdx.x];
  short4 o;
  o.x = f32_bf16(v.x*scale*wv.x);
  o.y = f32_bf16(v.y*scale*wv.y);
  o.z = f32_bf16(v.z*scale*wv.z);
  o.w = f32_bf16(v.w*scale*wv.w);
  ((short4*)out)[(size_t)row*256 + threadIdx.x] = o;
}

// ---------------- merged weight repack: wqkv^T (q pre-scaled by log2e) + wo^T --
__global__ __launch_bounds__(256) void pack_w_k(const float* __restrict__ wq,
                                                const float* __restrict__ wk,
                                                const float* __restrict__ wv,
                                                const float* __restrict__ wo,
                                                short* __restrict__ oqkv,
                                                short* __restrict__ owo) {
  int t = blockIdx.x*256 + threadIdx.x;   // 4M elements total
  if (t < 3072*1024) {
    int n = t >> 10, k = t & 1023;
    const float* src = (n < 1024) ? wq : ((n < 2048) ? wk : wv);
    float scale = (n < 1024) ? 1.44269504f : 1.0f;
    oqkv[t] = f32_bf16(src[(size_t)k*1024 + (n & 1023)] * scale);
  } else {
    int t2 = t - 3072*1024;
    int n = t2 >> 10, k = t2 & 1023;
    owo[t2] = f32_bf16(wo[(size_t)k*1024 + n]);
  }
}

// ---------------- GEMM: C[M,N] = A[M,K] * Bt[N,K]^T (+residual) ----------------
// v3: BK=32, double-buffered LDS, SINGLE barrier per k-iter with prefetch
// issued at the top of the body (flash-proven shape), XOR chunk swizzle.
template<bool ADD_RES>
__global__ __launch_bounds__(256) void gemm_bt(const short* __restrict__ A,
                                               const short* __restrict__ Bt,
                                               short* __restrict__ Cb,
                                               float* __restrict__ Cf,
                                               const float* __restrict__ res,
                                               int M, int N, int K) {
  constexpr int BK = 32;
  __shared__ __align__(16) short As[2][128*BK];   // 8 KB per buffer
  __shared__ __align__(16) short Bs[2][128*BK];
  int tid = threadIdx.x;
  int w = tid >> 6, lane = tid & 63, quad = lane >> 4, l16 = lane & 15;
  int wr = w >> 1, wc = w & 1;
  int bn = blockIdx.x, bm = blockIdx.y;
  const short* Ag = A + (size_t)bm * 128 * K;
  const short* Bg = Bt + (size_t)bn * 128 * K;
  const int r4 = lane >> 2;            // 0..15 (row within 16-row group)
  const int c4 = lane & 3;             // phys chunk 0..3
  const int lc = c4 ^ (r4 & 3);        // logical chunk (XOR swizzle)
  const int swz = (quad ^ (l16 & 3)) * 8;   // fragment-read chunk offset

  floatx4 acc[4][4] = {};

  // stage k-tile (k0) of A and B into buffer p_: rows c*16+r4, phys chunk c4
  #define GSTAGE(p_, k0_) do {                                                  \
    _Pragma("unroll")                                                           \
    for (int i = 0; i < 2; i++) {                                               \
      int c = w + i*4;                                                          \
      gload16(Ag + (size_t)(c*16 + r4) * K + (k0_) + lc*8, &As[p_][c*16*BK]);   \
      gload16(Bg + (size_t)(c*16 + r4) * K + (k0_) + lc*8, &Bs[p_][c*16*BK]);   \
    }                                                                           \
  } while (0)

  GSTAGE(0, 0);
  int p = 0;
  for (int k0 = 0; k0 < K; k0 += BK) {
    __syncthreads();                    // buffer p staged (vmcnt drained here)
    if (k0 + BK < K) GSTAGE(p ^ 1, k0 + BK);   // prefetch a full body ahead
    bf16x8 af[4], bfr[4];
    #pragma unroll
    for (int i = 0; i < 4; i++) {
      af[i]  = *(const bf16x8*)&As[p][(wr*64 + i*16 + l16)*BK + swz];
      bfr[i] = *(const bf16x8*)&Bs[p][(wc*64 + i*16 + l16)*BK + swz];
    }
    #pragma unroll
    for (int i = 0; i < 4; i++)
      #pragma unroll
      for (int j = 0; j < 4; j++)
        acc[i][j] = __builtin_amdgcn_mfma_f32_16x16x32_bf16(af[i], bfr[j], acc[i][j], 0, 0, 0);
    p ^= 1;
  }
  #undef GSTAGE

  #pragma unroll
  for (int i = 0; i < 4; i++) {
    int row0 = bm*128 + wr*64 + i*16 + quad*4;
    #pragma unroll
    for (int j = 0; j < 4; j++) {
      int col = bn*128 + wc*64 + j*16 + l16;
      #pragma unroll
      for (int r = 0; r < 4; r++) {
        size_t idx = (size_t)(row0 + r) * N + col;
        if (ADD_RES) Cf[idx] = res[idx] + acc[i][j][r];
        else         Cb[idx] = f32_bf16(acc[i][j][r]);
      }
    }
  }
}

// ---------------- V transpose pack: vt[bh][hd][s] ----------------
__global__ __launch_bounds__(256) void pack_vt_k(const short* __restrict__ qkv,
                                                 short* __restrict__ vt) {
  __shared__ __align__(16) short tile[64][72];
  int s0 = blockIdx.x * 64;
  int bh = blockIdx.y;
  int b = bh >> 4, h = bh & 15;
  int t = threadIdx.x;
  #pragma unroll
  for (int i = 0; i < 2; i++) {
    int idx = t + i*256;
    int s = idx >> 3, c = idx & 7;
    *(bf16x8*)&tile[s][c*8] =
      *(const bf16x8*)&qkv[(size_t)(b*S_LEN + s0 + s)*3072 + 2048 + h*64 + c*8];
  }
  __syncthreads();
  #pragma unroll
  for (int i = 0; i < 2; i++) {
    int idx = t + i*256;
    int hd = idx >> 3, c = idx & 7;
    short tmp[8];
    #pragma unroll
    for (int j = 0; j < 8; j++) tmp[j] = tile[c*8 + j][hd];
    *(bf16x8*)&vt[((size_t)(bh*64 + hd))*S_LEN + s0 + c*8] = *(bf16x8*)tmp;
  }
}

// ---------------- Flash attention v6: 256 queries/block (512 threads),
// XCD-swizzled bh grouping, prefetch at top, transposed-score softmax.
__global__ __launch_bounds__(512) void flash_k(const short* __restrict__ qkv,
                                               const short* __restrict__ vt,
                                               const float* __restrict__ rel_emb,
                                               short* __restrict__ ctx) {
  __shared__ __align__(16) short Kb[2][64*64];   // rows = permuted keys, cols = d
  __shared__ __align__(16) short Vb[2][64*64];   // rows = hd, cols = keys (natural)
  __shared__ float lut2[132];                    // bias * log2(e)

  const int L = blockIdx.x + 8*blockIdx.y;   // grid (8,64) = 512 blocks
  const int xcd = L & 7, kk_ = L >> 3;
  const int bh = xcd*8 + (kk_ >> 3);
  const int qt = kk_ & 7;
  const int b = bh >> 4, h = bh & 15;
  const int t = threadIdx.x, w = t >> 6, lane = t & 63, quad = lane >> 4, l16 = lane & 15;
  const float L2E = 1.44269504f;

  if (t < 129) {
    int rp = t, bucket;
    if (rp < 16) bucket = rp;
    else {
      bucket = 16 + (int)(logf((float)rp * 0.0625f) * (16.f / logf(8.f)));
      if (bucket > 31) bucket = 31;
    }
    lut2[t] = rel_emb[bucket*16 + h] * L2E;
  }
  const float bfut  = rel_emb[h] * L2E;            // d <= 0  -> bucket 0
  const float bpast = rel_emb[31*16 + h] * L2E;    // d >= 128 -> bucket 31
  const floatx4 bf4 = {bfut, bfut, bfut, bfut};
  const floatx4 bp4 = {bpast, bpast, bpast, bpast};
  const floatx4 zz4 = {0.f, 0.f, 0.f, 0.f};

  const int srow = lane >> 3;          // 0..7
  const int slc  = (lane & 7) ^ srow;  // XOR chunk swizzle
  const int rho  = w*8 + srow;
  const int kperm = 32*(rho >> 5) + 8*((rho >> 2) & 3) + 4*((rho >> 4) & 1) + (rho & 3);

  const short* kgU = qkv + ((size_t)b*S_LEN)*3072 + 1024 + h*64;  // wave-uniform
  const int    loK = kperm*3072 + slc*8;                           // lane-const
  const short* vgU = vt + ((size_t)bh*64)*2048;
  const int    loV = rho*2048 + slc*8;

  bf16x8 qB[2][2];
  #pragma unroll
  for (int rb = 0; rb < 2; rb++) {
    const short* qb = qkv + ((size_t)(b*S_LEN + qt*256 + rb*128 + w*16 + l16))*3072 + h*64;
    qB[rb][0] = *(const bf16x8*)&qb[quad*8];
    qB[rb][1] = *(const bf16x8*)&qb[32 + quad*8];
  }

  floatx4 o[2][4] = {};      // O^T accumulators: row=d(quad*4+r), col=query(l16)
  floatx4 li4[2] = {};       // row sums per query
  const short ONE = (short)0x3F80;
  bf16x8 onesA = {ONE, ONE, ONE, ONE, ONE, ONE, ONE, ONE};

  const int swz0 = (quad     ^ (l16 & 7)) * 8;
  const int swz1 = ((quad+4) ^ (l16 & 7)) * 8;

  #define STAGE(P_, KT_) do {                                                   \
    const short* ka_ = kgU + (size_t)(KT_)*196608 + loK;                        \
    gload16(ka_, &Kb[P_][(w*8)*64]);                                            \
    const short* va_ = vgU + loV + (KT_)*64;                                    \
    gload16(va_, &Vb[P_][(w*8)*64]);                                            \
  } while (0)

  #define BODY(P_, KT_) do {                                                    \
    __syncthreads();                                                            \
    if ((KT_) < 31) STAGE((P_) ^ 1, (KT_) + 1);   /* max prefetch distance */   \
    bool boundary = ((KT_) >= 4*qt - 2) && ((KT_) <= 4*qt + 3);                 \
    floatx4 cinit = boundary ? zz4 : (((KT_) >= 4*qt) ? bf4 : bp4);             \
    floatx4 sc[2][4];                                                           \
    _Pragma("unroll")                                                           \
    for (int c = 0; c < 4; c++) {                                               \
      int rowA = (c*16 + l16)*64;                                               \
      bf16x8 ka0 = *(const bf16x8*)&Kb[P_][rowA + swz0];                        \
      bf16x8 ka1 = *(const bf16x8*)&Kb[P_][rowA + swz1];                        \
      _Pragma("unroll")                                                         \
      for (int rb = 0; rb < 2; rb++) {                                          \
        floatx4 z = __builtin_amdgcn_mfma_f32_16x16x32_bf16(ka0, qB[rb][0], cinit, 0, 0, 0); \
        z = __builtin_amdgcn_mfma_f32_16x16x32_bf16(ka1, qB[rb][1], z, 0, 0, 0);\
        sc[rb][c] = z;                                                          \
      }                                                                         \
    }                                                                           \
    if (boundary) {                                                             \
      _Pragma("unroll")                                                         \
      for (int rb = 0; rb < 2; rb++) {                                          \
        int q0 = qt*256 + rb*128 + w*16 + l16;                                  \
        _Pragma("unroll")                                                       \
        for (int c = 0; c < 4; c++) {                                           \
          int kk = (KT_)*64 + 32*(c >> 1) + 8*quad + 4*(c & 1);                 \
          _Pragma("unroll")                                                     \
          for (int r = 0; r < 4; r++) {                                         \
            int d = q0 - (kk + r);                                              \
            d = d < 0 ? 0 : (d > 128 ? 128 : d);                                \
            sc[rb][c][r] += lut2[d];                                            \
          }                                                                     \
        }                                                                       \
      }                                                                         \
    }                                                                           \
    _Pragma("unroll")                                                           \
    for (int rb = 0; rb < 2; rb++)                                              \
      _Pragma("unroll")                                                         \
      for (int c = 0; c < 4; c++)                                               \
        _Pragma("unroll")                                                       \
        for (int r = 0; r < 4; r++)                                             \
          sc[rb][c][r] = exp2_fast(sc[rb][c][r]);                               \
    bf16x8 pf[2][2];                                                            \
    _Pragma("unroll")                                                           \
    for (int rb = 0; rb < 2; rb++) {                                            \
      _Pragma("unroll")                                                         \
      for (int hh = 0; hh < 2; hh++) {                                          \
        union { bf16x8 v; unsigned u[4]; } pk;                                  \
        floatx4 a = sc[rb][2*hh], bb = sc[rb][2*hh + 1];                        \
        pk.u[0] = __builtin_amdgcn_perm(__float_as_uint(a[1]),  __float_as_uint(a[0]),  0x07060302); \
        pk.u[1] = __builtin_amdgcn_perm(__float_as_uint(a[3]),  __float_as_uint(a[2]),  0x07060302); \
        pk.u[2] = __builtin_amdgcn_perm(__float_as_uint(bb[1]), __float_as_uint(bb[0]), 0x07060302); \
        pk.u[3] = __builtin_amdgcn_perm(__float_as_uint(bb[3]), __float_as_uint(bb[2]), 0x07060302); \
        pf[rb][hh] = pk.v;                                                      \
      }                                                                         \
    }                                                                           \
    _Pragma("unroll")                                                           \
    for (int rb = 0; rb < 2; rb++) {                                            \
      li4[rb] = __builtin_amdgcn_mfma_f32_16x16x32_bf16(onesA, pf[rb][0], li4[rb], 0, 0, 0); \
      li4[rb] = __builtin_amdgcn_mfma_f32_16x16x32_bf16(onesA, pf[rb][1], li4[rb], 0, 0, 0); \
    }                                                                           \
    _Pragma("unroll")                                                           \
    for (int jj = 0; jj < 4; jj++) {                                            \
      int rowV = (jj*16 + l16)*64;                                              \
      bf16x8 va0 = *(const bf16x8*)&Vb[P_][rowV + swz0];                        \
      bf16x8 va1 = *(const bf16x8*)&Vb[P_][rowV + swz1];                        \
      _Pragma("unroll")                                                         \
      for (int rb = 0; rb < 2; rb++) {                                          \
        o[rb][jj] = __builtin_amdgcn_mfma_f32_16x16x32_bf16(va0, pf[rb][0], o[rb][jj], 0, 0, 0); \
        o[rb][jj] = __builtin_amdgcn_mfma_f32_16x16x32_bf16(va1, pf[rb][1], o[rb][jj], 0, 0, 0); \
      }                                                                         \
    }                                                                           \
  } while (0)

  STAGE(0, 0);
  for (int kt = 0; kt < 32; kt += 2) {
    BODY(0, kt);
    BODY(1, kt + 1);
  }

  // ---- epilogue: normalize (per-query sum is lane-local) and store ----
  #pragma unroll
  for (int rb = 0; rb < 2; rb++) {
    float inv = 1.f / li4[rb][0];
    size_t row = (size_t)(b*S_LEN + qt*256 + rb*128 + w*16 + l16);
    #pragma unroll
    for (int jj = 0; jj < 4; jj++) {
      short4 st;
      st.x = f32_bf16(o[rb][jj][0] * inv);
      st.y = f32_bf16(o[rb][jj][1] * inv);
      st.z = f32_bf16(o[rb][jj][2] * inv);
      st.w = f32_bf16(o[rb][jj][3] * inv);
      *(short4*)&ctx[row*1024 + h*64 + jj*16 + quad*4] = st;
    }
  }
  #undef STAGE
  #undef BODY
}

extern "C" void kernel_launch(void* const* d_in, const int* in_sizes, int n_in,
                              void* d_out, int out_size, void* d_ws, size_t ws_size,
                              hipStream_t stream) {
  const float* input_ids = (const float*)d_in[0];
  // d_in[1] = encoder_output (unused by the reference computation)
  const float* wq      = (const float*)d_in[2];
  const float* wk      = (const float*)d_in[3];
  const float* wv      = (const float*)d_in[4];
  const float* wo      = (const float*)d_in[5];
  const float* rel_emb = (const float*)d_in[6];
  const float* ln_w    = (const float*)d_in[7];
  float* out = (float*)d_out;

  char* ws = (char*)d_ws;
  short* xb     = (short*)ws;  ws += (size_t)8192*1024*2;   // 16 MB
  short* wqkv_t = (short*)ws;  ws += (size_t)3072*1024*2;   // 6 MB
  short* wo_t   = (short*)ws;  ws += (size_t)1024*1024*2;   // 2 MB
  short* qkv    = (short*)ws;  ws += (size_t)8192*3072*2;   // 50 MB
  short* vt     = (short*)ws;  ws += (size_t)64*64*2048*2;  // 16 MB
  short* ctx    = (short*)ws;  ws += (size_t)8192*1024*2;   // 16 MB

  rmsnorm_k<<<8192, 256, 0, stream>>>(input_ids, ln_w, xb);
  pack_w_k<<<16384, 256, 0, stream>>>(wq, wk, wv, wo, wqkv_t, wo_t);
  gemm_bt<false><<<dim3(24, 64), 256, 0, stream>>>(xb, wqkv_t, qkv, nullptr, nullptr,
                                                   8192, 3072, 1024);
  pack_vt_k<<<dim3(32, 64), 256, 0, stream>>>(qkv, vt);
  flash_k<<<dim3(8, 64), 512, 0, stream>>>(qkv, vt, rel_emb, ctx);
  gemm_bt<true><<<dim3(8, 64), 256, 0, stream>>>(ctx, wo_t, nullptr, out, input_ids,
                                                 8192, 1024, 1024);
}

// Round 9
// 290.857 us; speedup vs baseline: 1.6809x; 1.0050x over previous
//
#include <hip/hip_runtime.h>
#include <hip/hip_bf16.h>
#include <math.h>

#define S_LEN 2048
#define D_DIM 1024
#define NHEAD 16

typedef __attribute__((ext_vector_type(8))) short bf16x8;
typedef __attribute__((ext_vector_type(4))) float floatx4;

__device__ __forceinline__ short f32_bf16(float f) {
  union { float f; unsigned u; } v; v.f = f;
  unsigned r = v.u + 0x7FFFu + ((v.u >> 16) & 1u);
  return (short)(r >> 16);
}

__device__ __forceinline__ float exp2_fast(float x) {
#if __has_builtin(__builtin_amdgcn_exp2f)
  return __builtin_amdgcn_exp2f(x);
#else
  float r; asm("v_exp_f32 %0, %1" : "=v"(r) : "v"(x)); return r;
#endif
}

__device__ __forceinline__ void gload16(const void* g, void* l) {
  __builtin_amdgcn_global_load_lds((const __attribute__((address_space(1))) unsigned*)g,
                                   (__attribute__((address_space(3))) unsigned*)l,
                                   16, 0, 0);
}

// ---------------- prep: RMSNorm (blocks 0..8191) + weight repack (rest) -------
__global__ __launch_bounds__(256) void prep_k(const float* __restrict__ x,
                                              const float* __restrict__ lnw,
                                              const float* __restrict__ wq,
                                              const float* __restrict__ wk,
                                              const float* __restrict__ wv,
                                              const float* __restrict__ wo,
                                              short* __restrict__ xb,
                                              short* __restrict__ oqkv,
                                              short* __restrict__ owo) {
  if (blockIdx.x < 8192) {
    int row = blockIdx.x;
    const float4* xr = (const float4*)(x + (size_t)row * D_DIM);
    float4 v = xr[threadIdx.x];
    float ss = v.x*v.x + v.y*v.y + v.z*v.z + v.w*v.w;
    #pragma unroll
    for (int off = 32; off > 0; off >>= 1) ss += __shfl_xor(ss, off);
    __shared__ float red[4];
    if ((threadIdx.x & 63) == 0) red[threadIdx.x >> 6] = ss;
    __syncthreads();
    float scale = rsqrtf((red[0]+red[1]+red[2]+red[3]) * (1.f/D_DIM) + 1e-6f);
    float4 wv4 = ((const float4*)lnw)[threadIdx.x];
    short4 o;
    o.x = f32_bf16(v.x*scale*wv4.x);
    o.y = f32_bf16(v.y*scale*wv4.y);
    o.z = f32_bf16(v.z*scale*wv4.z);
    o.w = f32_bf16(v.w*scale*wv4.w);
    ((short4*)xb)[(size_t)row*256 + threadIdx.x] = o;
  } else {
    int t = (blockIdx.x - 8192)*256 + threadIdx.x;   // 4M elements
    if (t < 3072*1024) {
      int n = t >> 10, k = t & 1023;
      const float* src = (n < 1024) ? wq : ((n < 2048) ? wk : wv);
      float scale = (n < 1024) ? 1.44269504f : 1.0f;
      oqkv[t] = f32_bf16(src[(size_t)k*1024 + (n & 1023)] * scale);
    } else {
      int t2 = t - 3072*1024;
      int n = t2 >> 10, k = t2 & 1023;
      owo[t2] = f32_bf16(wo[(size_t)k*1024 + n]);
    }
  }
}

// ---------------- GEMM: C[M,N] = A[M,K] * Bt[N,K]^T (+residual) ----------------
// v4: single-barrier double-buffered K-loop (prefetch at top), XOR chunk swizzle,
// XCD-panel remap: 1D grid, xcd = id&7 owns bn-panel [xcd*PANELS, ...), bm-major
// inner order -> per-XCD B-panel stays L2-resident, A-tiles reused x PANELS.
template<bool ADD_RES, int PANELS>
__global__ __launch_bounds__(256) void gemm_bt(const short* __restrict__ A,
                                               const short* __restrict__ Bt,
                                               short* __restrict__ Cb,
                                               float* __restrict__ Cf,
                                               const float* __restrict__ res,
                                               int M, int N, int K) {
  constexpr int BK = 32;
  __shared__ __align__(16) short As[2][128*BK];   // 8 KB per buffer
  __shared__ __align__(16) short Bs[2][128*BK];
  int tid = threadIdx.x;
  int w = tid >> 6, lane = tid & 63, quad = lane >> 4, l16 = lane & 15;
  int wr = w >> 1, wc = w & 1;
  const int id = blockIdx.x;
  const int xcd = id & 7, g = id >> 3;
  const int bm = g / PANELS;
  const int bn = xcd * PANELS + (g % PANELS);
  const short* Ag = A + (size_t)bm * 128 * K;
  const short* Bg = Bt + (size_t)bn * 128 * K;
  const int r4 = lane >> 2;            // 0..15 (row within 16-row group)
  const int c4 = lane & 3;             // phys chunk 0..3
  const int lc = c4 ^ (r4 & 3);        // logical chunk (XOR swizzle)
  const int swz = (quad ^ (l16 & 3)) * 8;   // fragment-read chunk offset

  floatx4 acc[4][4] = {};

  #define GSTAGE(p_, k0_) do {                                                  \
    _Pragma("unroll")                                                           \
    for (int i = 0; i < 2; i++) {                                               \
      int c = w + i*4;                                                          \
      gload16(Ag + (size_t)(c*16 + r4) * K + (k0_) + lc*8, &As[p_][c*16*BK]);   \
      gload16(Bg + (size_t)(c*16 + r4) * K + (k0_) + lc*8, &Bs[p_][c*16*BK]);   \
    }                                                                           \
  } while (0)

  GSTAGE(0, 0);
  int p = 0;
  for (int k0 = 0; k0 < K; k0 += BK) {
    __syncthreads();                    // buffer p staged (vmcnt drained here)
    if (k0 + BK < K) GSTAGE(p ^ 1, k0 + BK);   // prefetch a full body ahead
    bf16x8 af[4], bfr[4];
    #pragma unroll
    for (int i = 0; i < 4; i++) {
      af[i]  = *(const bf16x8*)&As[p][(wr*64 + i*16 + l16)*BK + swz];
      bfr[i] = *(const bf16x8*)&Bs[p][(wc*64 + i*16 + l16)*BK + swz];
    }
    #pragma unroll
    for (int i = 0; i < 4; i++)
      #pragma unroll
      for (int j = 0; j < 4; j++)
        acc[i][j] = __builtin_amdgcn_mfma_f32_16x16x32_bf16(af[i], bfr[j], acc[i][j], 0, 0, 0);
    p ^= 1;
  }
  #undef GSTAGE

  #pragma unroll
  for (int i = 0; i < 4; i++) {
    int row0 = bm*128 + wr*64 + i*16 + quad*4;
    #pragma unroll
    for (int j = 0; j < 4; j++) {
      int col = bn*128 + wc*64 + j*16 + l16;
      #pragma unroll
      for (int r = 0; r < 4; r++) {
        size_t idx = (size_t)(row0 + r) * N + col;
        if (ADD_RES) Cf[idx] = res[idx] + acc[i][j][r];
        else         Cb[idx] = f32_bf16(acc[i][j][r]);
      }
    }
  }
}

// ---------------- V transpose pack: vt[bh][hd][s] ----------------
__global__ __launch_bounds__(256) void pack_vt_k(const short* __restrict__ qkv,
                                                 short* __restrict__ vt) {
  __shared__ __align__(16) short tile[64][72];
  int s0 = blockIdx.x * 64;
  int bh = blockIdx.y;
  int b = bh >> 4, h = bh & 15;
  int t = threadIdx.x;
  #pragma unroll
  for (int i = 0; i < 2; i++) {
    int idx = t + i*256;
    int s = idx >> 3, c = idx & 7;
    *(bf16x8*)&tile[s][c*8] =
      *(const bf16x8*)&qkv[(size_t)(b*S_LEN + s0 + s)*3072 + 2048 + h*64 + c*8];
  }
  __syncthreads();
  #pragma unroll
  for (int i = 0; i < 2; i++) {
    int idx = t + i*256;
    int hd = idx >> 3, c = idx & 7;
    short tmp[8];
    #pragma unroll
    for (int j = 0; j < 8; j++) tmp[j] = tile[c*8 + j][hd];
    *(bf16x8*)&vt[((size_t)(bh*64 + hd))*S_LEN + s0 + c*8] = *(bf16x8*)tmp;
  }
}

// ---------------- Flash attention v6: 256 queries/block (512 threads),
// XCD-swizzled bh grouping, prefetch at top, transposed-score softmax.
__global__ __launch_bounds__(512) void flash_k(const short* __restrict__ qkv,
                                               const short* __restrict__ vt,
                                               const float* __restrict__ rel_emb,
                                               short* __restrict__ ctx) {
  __shared__ __align__(16) short Kb[2][64*64];   // rows = permuted keys, cols = d
  __shared__ __align__(16) short Vb[2][64*64];   // rows = hd, cols = keys (natural)
  __shared__ float lut2[132];                    // bias * log2(e)

  const int L = blockIdx.x + 8*blockIdx.y;   // grid (8,64) = 512 blocks
  const int xcd = L & 7, kk_ = L >> 3;
  const int bh = xcd*8 + (kk_ >> 3);
  const int qt = kk_ & 7;
  const int b = bh >> 4, h = bh & 15;
  const int t = threadIdx.x, w = t >> 6, lane = t & 63, quad = lane >> 4, l16 = lane & 15;
  const float L2E = 1.44269504f;

  if (t < 129) {
    int rp = t, bucket;
    if (rp < 16) bucket = rp;
    else {
      bucket = 16 + (int)(logf((float)rp * 0.0625f) * (16.f / logf(8.f)));
      if (bucket > 31) bucket = 31;
    }
    lut2[t] = rel_emb[bucket*16 + h] * L2E;
  }
  const float bfut  = rel_emb[h] * L2E;            // d <= 0  -> bucket 0
  const float bpast = rel_emb[31*16 + h] * L2E;    // d >= 128 -> bucket 31
  const floatx4 bf4 = {bfut, bfut, bfut, bfut};
  const floatx4 bp4 = {bpast, bpast, bpast, bpast};
  const floatx4 zz4 = {0.f, 0.f, 0.f, 0.f};

  const int srow = lane >> 3;          // 0..7
  const int slc  = (lane & 7) ^ srow;  // XOR chunk swizzle
  const int rho  = w*8 + srow;
  const int kperm = 32*(rho >> 5) + 8*((rho >> 2) & 3) + 4*((rho >> 4) & 1) + (rho & 3);

  const short* kgU = qkv + ((size_t)b*S_LEN)*3072 + 1024 + h*64;  // wave-uniform
  const int    loK = kperm*3072 + slc*8;                           // lane-const
  const short* vgU = vt + ((size_t)bh*64)*2048;
  const int    loV = rho*2048 + slc*8;

  bf16x8 qB[2][2];
  #pragma unroll
  for (int rb = 0; rb < 2; rb++) {
    const short* qb = qkv + ((size_t)(b*S_LEN + qt*256 + rb*128 + w*16 + l16))*3072 + h*64;
    qB[rb][0] = *(const bf16x8*)&qb[quad*8];
    qB[rb][1] = *(const bf16x8*)&qb[32 + quad*8];
  }

  floatx4 o[2][4] = {};      // O^T accumulators: row=d(quad*4+r), col=query(l16)
  floatx4 li4[2] = {};       // row sums per query
  const short ONE = (short)0x3F80;
  bf16x8 onesA = {ONE, ONE, ONE, ONE, ONE, ONE, ONE, ONE};

  const int swz0 = (quad     ^ (l16 & 7)) * 8;
  const int swz1 = ((quad+4) ^ (l16 & 7)) * 8;

  #define STAGE(P_, KT_) do {                                                   \
    const short* ka_ = kgU + (size_t)(KT_)*196608 + loK;                        \
    gload16(ka_, &Kb[P_][(w*8)*64]);                                            \
    const short* va_ = vgU + loV + (KT_)*64;                                    \
    gload16(va_, &Vb[P_][(w*8)*64]);                                            \
  } while (0)

  #define BODY(P_, KT_) do {                                                    \
    __syncthreads();                                                            \
    if ((KT_) < 31) STAGE((P_) ^ 1, (KT_) + 1);   /* max prefetch distance */   \
    bool boundary = ((KT_) >= 4*qt - 2) && ((KT_) <= 4*qt + 3);                 \
    floatx4 cinit = boundary ? zz4 : (((KT_) >= 4*qt) ? bf4 : bp4);             \
    floatx4 sc[2][4];                                                           \
    _Pragma("unroll")                                                           \
    for (int c = 0; c < 4; c++) {                                               \
      int rowA = (c*16 + l16)*64;                                               \
      bf16x8 ka0 = *(const bf16x8*)&Kb[P_][rowA + swz0];                        \
      bf16x8 ka1 = *(const bf16x8*)&Kb[P_][rowA + swz1];                        \
      _Pragma("unroll")                                                         \
      for (int rb = 0; rb < 2; rb++) {                                          \
        floatx4 z = __builtin_amdgcn_mfma_f32_16x16x32_bf16(ka0, qB[rb][0], cinit, 0, 0, 0); \
        z = __builtin_amdgcn_mfma_f32_16x16x32_bf16(ka1, qB[rb][1], z, 0, 0, 0);\
        sc[rb][c] = z;                                                          \
      }                                                                         \
    }                                                                           \
    if (boundary) {                                                             \
      _Pragma("unroll")                                                         \
      for (int rb = 0; rb < 2; rb++) {                                          \
        int q0 = qt*256 + rb*128 + w*16 + l16;                                  \
        _Pragma("unroll")                                                       \
        for (int c = 0; c < 4; c++) {                                           \
          int kk = (KT_)*64 + 32*(c >> 1) + 8*quad + 4*(c & 1);                 \
          _Pragma("unroll")                                                     \
          for (int r = 0; r < 4; r++) {                                         \
            int d = q0 - (kk + r);                                              \
            d = d < 0 ? 0 : (d > 128 ? 128 : d);                                \
            sc[rb][c][r] += lut2[d];                                            \
          }                                                                     \
        }                                                                       \
      }                                                                         \
    }                                                                           \
    _Pragma("unroll")                                                           \
    for (int rb = 0; rb < 2; rb++)                                              \
      _Pragma("unroll")                                                         \
      for (int c = 0; c < 4; c++)                                               \
        _Pragma("unroll")                                                       \
        for (int r = 0; r < 4; r++)                                             \
          sc[rb][c][r] = exp2_fast(sc[rb][c][r]);                               \
    bf16x8 pf[2][2];                                                            \
    _Pragma("unroll")                                                           \
    for (int rb = 0; rb < 2; rb++) {                                            \
      _Pragma("unroll")                                                         \
      for (int hh = 0; hh < 2; hh++) {                                          \
        union { bf16x8 v; unsigned u[4]; } pk;                                  \
        floatx4 a = sc[rb][2*hh], bb = sc[rb][2*hh + 1];                        \
        pk.u[0] = __builtin_amdgcn_perm(__float_as_uint(a[1]),  __float_as_uint(a[0]),  0x07060302); \
        pk.u[1] = __builtin_amdgcn_perm(__float_as_uint(a[3]),  __float_as_uint(a[2]),  0x07060302); \
        pk.u[2] = __builtin_amdgcn_perm(__float_as_uint(bb[1]), __float_as_uint(bb[0]), 0x07060302); \
        pk.u[3] = __builtin_amdgcn_perm(__float_as_uint(bb[3]), __float_as_uint(bb[2]), 0x07060302); \
        pf[rb][hh] = pk.v;                                                      \
      }                                                                         \
    }                                                                           \
    _Pragma("unroll")                                                           \
    for (int rb = 0; rb < 2; rb++) {                                            \
      li4[rb] = __builtin_amdgcn_mfma_f32_16x16x32_bf16(onesA, pf[rb][0], li4[rb], 0, 0, 0); \
      li4[rb] = __builtin_amdgcn_mfma_f32_16x16x32_bf16(onesA, pf[rb][1], li4[rb], 0, 0, 0); \
    }                                                                           \
    _Pragma("unroll")                                                           \
    for (int jj = 0; jj < 4; jj++) {                                            \
      int rowV = (jj*16 + l16)*64;                                              \
      bf16x8 va0 = *(const bf16x8*)&Vb[P_][rowV + swz0];                        \
      bf16x8 va1 = *(const bf16x8*)&Vb[P_][rowV + swz1];                        \
      _Pragma("unroll")                                                         \
      for (int rb = 0; rb < 2; rb++) {                                          \
        o[rb][jj] = __builtin_amdgcn_mfma_f32_16x16x32_bf16(va0, pf[rb][0], o[rb][jj], 0, 0, 0); \
        o[rb][jj] = __builtin_amdgcn_mfma_f32_16x16x32_bf16(va1, pf[rb][1], o[rb][jj], 0, 0, 0); \
      }                                                                         \
    }                                                                           \
  } while (0)

  STAGE(0, 0);
  for (int kt = 0; kt < 32; kt += 2) {
    BODY(0, kt);
    BODY(1, kt + 1);
  }

  // ---- epilogue: normalize (per-query sum is lane-local) and store ----
  #pragma unroll
  for (int rb = 0; rb < 2; rb++) {
    float inv = 1.f / li4[rb][0];
    size_t row = (size_t)(b*S_LEN + qt*256 + rb*128 + w*16 + l16);
    #pragma unroll
    for (int jj = 0; jj < 4; jj++) {
      short4 st;
      st.x = f32_bf16(o[rb][jj][0] * inv);
      st.y = f32_bf16(o[rb][jj][1] * inv);
      st.z = f32_bf16(o[rb][jj][2] * inv);
      st.w = f32_bf16(o[rb][jj][3] * inv);
      *(short4*)&ctx[row*1024 + h*64 + jj*16 + quad*4] = st;
    }
  }
  #undef STAGE
  #undef BODY
}

extern "C" void kernel_launch(void* const* d_in, const int* in_sizes, int n_in,
                              void* d_out, int out_size, void* d_ws, size_t ws_size,
                              hipStream_t stream) {
  const float* input_ids = (const float*)d_in[0];
  // d_in[1] = encoder_output (unused by the reference computation)
  const float* wq      = (const float*)d_in[2];
  const float* wk      = (const float*)d_in[3];
  const float* wv      = (const float*)d_in[4];
  const float* wo      = (const float*)d_in[5];
  const float* rel_emb = (const float*)d_in[6];
  const float* ln_w    = (const float*)d_in[7];
  float* out = (float*)d_out;

  char* ws = (char*)d_ws;
  short* xb     = (short*)ws;  ws += (size_t)8192*1024*2;   // 16 MB
  short* wqkv_t = (short*)ws;  ws += (size_t)3072*1024*2;   // 6 MB
  short* wo_t   = (short*)ws;  ws += (size_t)1024*1024*2;   // 2 MB
  short* qkv    = (short*)ws;  ws += (size_t)8192*3072*2;   // 50 MB
  short* vt     = (short*)ws;  ws += (size_t)64*64*2048*2;  // 16 MB
  short* ctx    = (short*)ws;  ws += (size_t)8192*1024*2;   // 16 MB

  prep_k<<<8192 + 16384, 256, 0, stream>>>(input_ids, ln_w, wq, wk, wv, wo,
                                           xb, wqkv_t, wo_t);
  gemm_bt<false, 3><<<1536, 256, 0, stream>>>(xb, wqkv_t, qkv, nullptr, nullptr,
                                              8192, 3072, 1024);
  pack_vt_k<<<dim3(32, 64), 256, 0, stream>>>(qkv, vt);
  flash_k<<<dim3(8, 64), 512, 0, stream>>>(qkv, vt, rel_emb, ctx);
  gemm_bt<true, 1><<<512, 256, 0, stream>>>(ctx, wo_t, nullptr, out, input_ids,
                                            8192, 1024, 1024);
}